// Round 1
// baseline (907.569 us; speedup 1.0000x reference)
//
#include <hip/hip_runtime.h>
#include <hip/hip_bf16.h>
#include <math.h>

#define S_LEN 2048
#define HIDDEN 4096
#define NH 32
#define NKV 8
#define HD 128

typedef __bf16 bf16_t;
typedef __bf16 bf16x8 __attribute__((ext_vector_type(8)));
typedef __bf16 bf16x4 __attribute__((ext_vector_type(4)));
typedef float f32x4 __attribute__((ext_vector_type(4)));

typedef __attribute__((address_space(1))) void gvoid;
typedef __attribute__((address_space(3))) void lvoid;

__device__ __forceinline__ void gload_lds16(const void* g, void* l) {
    __builtin_amdgcn_global_load_lds((gvoid*)g, (lvoid*)l, 16, 0, 0);
}

// ---------------- cast fp32 -> bf16 (vectorized) ----------------
__global__ void cast_bf16_kernel(const float* __restrict__ in, bf16_t* __restrict__ out, int n4) {
    int stride = gridDim.x * blockDim.x;
    for (int idx = blockIdx.x * blockDim.x + threadIdx.x; idx < n4; idx += stride) {
        float4 v = ((const float4*)in)[idx];
        bf16x4 o;
        o.x = (bf16_t)v.x; o.y = (bf16_t)v.y; o.z = (bf16_t)v.z; o.w = (bf16_t)v.w;
        ((bf16x4*)out)[idx] = o;
    }
}

// ---------------- transpose + cast: in[R][C] fp32 -> out[C][R] bf16 ----------------
__global__ __launch_bounds__(256) void transpose_cast_kernel(const float* __restrict__ in,
                                                             bf16_t* __restrict__ out,
                                                             int R, int C) {
    __shared__ float t[32][33];
    int c0 = blockIdx.x * 32, r0 = blockIdx.y * 32;
    int tx = threadIdx.x, ty = threadIdx.y;
#pragma unroll
    for (int i = 0; i < 4; ++i)
        t[ty + i * 8][tx] = in[(size_t)(r0 + ty + i * 8) * C + c0 + tx];
    __syncthreads();
#pragma unroll
    for (int i = 0; i < 4; ++i)
        out[(size_t)(c0 + ty + i * 8) * R + r0 + tx] = (bf16_t)t[tx][ty + i * 8];
}

// ---------------- GEMM: C[M][N] = A[M][K] @ Bt[N][K]^T, fp32 out ----------------
// 128x128 tile, 4 waves (each 64x64), BK=32, global_load_lds staging.
__global__ __launch_bounds__(256) void gemm_bt_kernel(const bf16_t* __restrict__ A,
                                                      const bf16_t* __restrict__ Bt,
                                                      float* __restrict__ C,
                                                      int M, int N, int K) {
    __shared__ bf16_t As[128 * 32];
    __shared__ bf16_t Bs[128 * 32];
    const int tid = threadIdx.x;
    const int lane = tid & 63, w = tid >> 6;
    const int wr = w >> 1, wc = w & 1;
    const int bm = blockIdx.y, bn = blockIdx.x;
    const int g = lane >> 4, c16 = lane & 15;
    const bf16_t* Ab = A + (size_t)bm * 128 * K;
    const bf16_t* Bb = Bt + (size_t)bn * 128 * K;

    f32x4 acc[4][4];
#pragma unroll
    for (int i = 0; i < 4; ++i)
#pragma unroll
        for (int j = 0; j < 4; ++j)
            acc[i][j] = (f32x4){0.f, 0.f, 0.f, 0.f};

    for (int kt = 0; kt < K; kt += 32) {
#pragma unroll
        for (int is = 0; is < 2; ++is) {
            int e = (is * 256 + tid) * 8;          // element index in 128x32 tile
            int row = e >> 5, col = e & 31;
            gload_lds16(Ab + (size_t)row * K + kt + col, As + (size_t)(is * 256 + w * 64) * 8);
            gload_lds16(Bb + (size_t)row * K + kt + col, Bs + (size_t)(is * 256 + w * 64) * 8);
        }
        __syncthreads();
        bf16x8 a[4], b[4];
#pragma unroll
        for (int mi = 0; mi < 4; ++mi)
            a[mi] = *(const bf16x8*)(As + (wr * 64 + mi * 16 + c16) * 32 + g * 8);
#pragma unroll
        for (int ni = 0; ni < 4; ++ni)
            b[ni] = *(const bf16x8*)(Bs + (wc * 64 + ni * 16 + c16) * 32 + g * 8);
#pragma unroll
        for (int mi = 0; mi < 4; ++mi)
#pragma unroll
            for (int ni = 0; ni < 4; ++ni)
                acc[mi][ni] = __builtin_amdgcn_mfma_f32_16x16x32_bf16(a[mi], b[ni], acc[mi][ni], 0, 0, 0);
        __syncthreads();
    }
#pragma unroll
    for (int mi = 0; mi < 4; ++mi)
#pragma unroll
        for (int ni = 0; ni < 4; ++ni) {
            int col = bn * 128 + wc * 64 + ni * 16 + c16;
#pragma unroll
            for (int r = 0; r < 4; ++r) {
                int row = bm * 128 + wr * 64 + mi * 16 + g * 4 + r;
                C[(size_t)row * N + col] = acc[mi][ni][r];
            }
        }
}

// ---------------- RoPE: in fp32 [S][H*128] -> out bf16 [H][S][128], scale folded ----------------
__global__ void rope_kernel(const float* __restrict__ in, bf16_t* __restrict__ out,
                            const int* __restrict__ pos, int H, float scale) {
    int idx = blockIdx.x * blockDim.x + threadIdx.x;
    int total = S_LEN * H * 64;
    if (idx >= total) return;
    int d = idx & 63;
    int h = (idx >> 6) % H;
    int s = idx / (64 * H);
    const float* base = in + (size_t)s * H * HD + h * HD;
    float x0 = base[d], x1 = base[d + 64];
    float p = (float)pos[s];
    float invf = __expf(-0.14391156831212787f * (float)d);  // ln(10000)/64
    float f = p * invf;
    float sn, cs;
    __sincosf(f, &sn, &cs);
    float o0 = (x0 * cs - x1 * sn) * scale;
    float o1 = (x1 * cs + x0 * sn) * scale;
    bf16_t* ob = out + ((size_t)h * S_LEN + s) * HD;
    ob[d] = (bf16_t)o0;
    ob[d + 64] = (bf16_t)o1;
}

// ---------------- flash attention ----------------
// grid (S/64, NH), block 256 (4 waves). wave w handles 16 q rows.
// Q bf16 [NH][S][128] (pre-scaled), K bf16 [NKV][S][128], Vt bf16 [NKV][128][S].
// O bf16 [S][NH*128].
__global__ __launch_bounds__(256) void attn_kernel(const bf16_t* __restrict__ Q,
                                                   const bf16_t* __restrict__ K,
                                                   const bf16_t* __restrict__ Vt,
                                                   bf16_t* __restrict__ O) {
    __shared__ bf16_t Pl[4][16 * 32];
    const int tid = threadIdx.x;
    const int lane = tid & 63, w = tid >> 6;
    const int h = blockIdx.y;
    const int kv = h >> 2;               // N_REP = 4
    const int qb = blockIdx.x * 64 + w * 16;
    const int g = lane >> 4, c16 = lane & 15;
    const bf16_t* Qh = Q + (size_t)h * S_LEN * HD;
    const bf16_t* Kh = K + (size_t)kv * S_LEN * HD;
    const bf16_t* Vh = Vt + (size_t)kv * HD * S_LEN;
    bf16_t* P = Pl[w];

    bf16x8 qf[4];
#pragma unroll
    for (int c = 0; c < 4; ++c)
        qf[c] = *(const bf16x8*)(Qh + (size_t)(qb + c16) * HD + c * 32 + g * 8);

    f32x4 acc_o[8];
#pragma unroll
    for (int dt = 0; dt < 8; ++dt) acc_o[dt] = (f32x4){0.f, 0.f, 0.f, 0.f};
    float m[4] = {-1e30f, -1e30f, -1e30f, -1e30f};
    float l[4] = {0.f, 0.f, 0.f, 0.f};

    const int nkt = blockIdx.x * 2 + 2;  // uniform per block (keeps barriers legal)
    for (int kt = 0; kt < nkt; ++kt) {
        const int kb = kt * 32;
        f32x4 sacc[2];
        sacc[0] = (f32x4){0.f, 0.f, 0.f, 0.f};
        sacc[1] = (f32x4){0.f, 0.f, 0.f, 0.f};
#pragma unroll
        for (int t = 0; t < 2; ++t)
#pragma unroll
            for (int c = 0; c < 4; ++c) {
                bf16x8 kf = *(const bf16x8*)(Kh + (size_t)(kb + t * 16 + c16) * HD + c * 32 + g * 8);
                sacc[t] = __builtin_amdgcn_mfma_f32_16x16x32_bf16(qf[c], kf, sacc[t], 0, 0, 0);
            }
        // mask + online softmax (rows live in regs r, k in lane&15 per 16-lane group)
        float p[2][4], alpha[4];
#pragma unroll
        for (int r = 0; r < 4; ++r) {
            int qq = qb + g * 4 + r;
            float s0 = (kb + c16 <= qq) ? sacc[0][r] : -1e30f;
            float s1 = (kb + 16 + c16 <= qq) ? sacc[1][r] : -1e30f;
            float mx = fmaxf(s0, s1);
            mx = fmaxf(mx, __shfl_xor(mx, 1));
            mx = fmaxf(mx, __shfl_xor(mx, 2));
            mx = fmaxf(mx, __shfl_xor(mx, 4));
            mx = fmaxf(mx, __shfl_xor(mx, 8));
            float mn = fmaxf(m[r], mx);
            alpha[r] = __expf(m[r] - mn);
            m[r] = mn;
            float p0 = __expf(s0 - mn);
            float p1 = __expf(s1 - mn);
            p[0][r] = p0; p[1][r] = p1;
            float rs = p0 + p1;
            rs += __shfl_xor(rs, 1);
            rs += __shfl_xor(rs, 2);
            rs += __shfl_xor(rs, 4);
            rs += __shfl_xor(rs, 8);
            l[r] = l[r] * alpha[r] + rs;
        }
#pragma unroll
        for (int dt = 0; dt < 8; ++dt)
#pragma unroll
            for (int r = 0; r < 4; ++r) acc_o[dt][r] *= alpha[r];
        // P -> LDS (C-layout to A-layout redistribution)
#pragma unroll
        for (int t = 0; t < 2; ++t)
#pragma unroll
            for (int r = 0; r < 4; ++r)
                P[(g * 4 + r) * 32 + t * 16 + c16] = (bf16_t)p[t][r];
        __syncthreads();
        bf16x8 pf = *(const bf16x8*)(P + c16 * 32 + g * 8);
#pragma unroll
        for (int dt = 0; dt < 8; ++dt) {
            bf16x8 vf = *(const bf16x8*)(Vh + (size_t)(dt * 16 + c16) * S_LEN + kb + g * 8);
            acc_o[dt] = __builtin_amdgcn_mfma_f32_16x16x32_bf16(pf, vf, acc_o[dt], 0, 0, 0);
        }
        __syncthreads();
    }
    float inv_l[4];
#pragma unroll
    for (int r = 0; r < 4; ++r) inv_l[r] = 1.f / l[r];
#pragma unroll
    for (int dt = 0; dt < 8; ++dt)
#pragma unroll
        for (int r = 0; r < 4; ++r)
            O[(size_t)(qb + g * 4 + r) * HIDDEN + h * HD + dt * 16 + c16] =
                (bf16_t)(acc_o[dt][r] * inv_l[r]);
}

// ---------------- host ----------------
extern "C" void kernel_launch(void* const* d_in, const int* in_sizes, int n_in,
                              void* d_out, int out_size, void* d_ws, size_t ws_size,
                              hipStream_t stream) {
    const float* hs = (const float*)d_in[0];
    const float* Wq = (const float*)d_in[1];
    const float* Wk = (const float*)d_in[2];
    const float* Wv = (const float*)d_in[3];
    const float* Wo = (const float*)d_in[4];
    const int* pos = (const int*)d_in[6];
    float* out = (float*)d_out;

    char* ws = (char*)d_ws;
    size_t off = 0;
    auto alloc = [&](size_t bytes) -> void* {
        void* p = ws + off;
        off += (bytes + 255) & ~(size_t)255;
        return p;
    };
    bf16_t* hB   = (bf16_t*)alloc((size_t)S_LEN * HIDDEN * 2);
    bf16_t* WqT  = (bf16_t*)alloc((size_t)HIDDEN * HIDDEN * 2);
    bf16_t* WkT  = (bf16_t*)alloc((size_t)1024 * HIDDEN * 2);
    bf16_t* WvT  = (bf16_t*)alloc((size_t)1024 * HIDDEN * 2);
    bf16_t* WoT  = (bf16_t*)alloc((size_t)HIDDEN * HIDDEN * 2);
    float*  Qpre = (float*)alloc((size_t)S_LEN * HIDDEN * 4);
    float*  Kpre = (float*)alloc((size_t)S_LEN * 1024 * 4);
    float*  Vpre = (float*)alloc((size_t)S_LEN * 1024 * 4);
    bf16_t* Qr   = (bf16_t*)alloc((size_t)NH * S_LEN * HD * 2);
    bf16_t* Kr   = (bf16_t*)alloc((size_t)NKV * S_LEN * HD * 2);
    bf16_t* Vt   = (bf16_t*)alloc((size_t)NKV * HD * S_LEN * 2);
    bf16_t* Oat  = (bf16_t*)alloc((size_t)S_LEN * HIDDEN * 2);

    // 1. cast hidden to bf16
    cast_bf16_kernel<<<2048, 256, 0, stream>>>(hs, hB, S_LEN * HIDDEN / 4);
    // 2. transpose-cast weights
    dim3 tb(32, 8);
    transpose_cast_kernel<<<dim3(HIDDEN / 32, HIDDEN / 32), tb, 0, stream>>>(Wq, WqT, HIDDEN, HIDDEN);
    transpose_cast_kernel<<<dim3(1024 / 32, HIDDEN / 32), tb, 0, stream>>>(Wk, WkT, HIDDEN, 1024);
    transpose_cast_kernel<<<dim3(1024 / 32, HIDDEN / 32), tb, 0, stream>>>(Wv, WvT, HIDDEN, 1024);
    transpose_cast_kernel<<<dim3(HIDDEN / 32, HIDDEN / 32), tb, 0, stream>>>(Wo, WoT, HIDDEN, HIDDEN);
    // 3. QKV projections
    gemm_bt_kernel<<<dim3(HIDDEN / 128, S_LEN / 128), 256, 0, stream>>>(hB, WqT, Qpre, S_LEN, HIDDEN, HIDDEN);
    gemm_bt_kernel<<<dim3(1024 / 128, S_LEN / 128), 256, 0, stream>>>(hB, WkT, Kpre, S_LEN, 1024, HIDDEN);
    gemm_bt_kernel<<<dim3(1024 / 128, S_LEN / 128), 256, 0, stream>>>(hB, WvT, Vpre, S_LEN, 1024, HIDDEN);
    // 4. RoPE (fold 1/sqrt(128) into Q)
    rope_kernel<<<(S_LEN * NH * 64 + 255) / 256, 256, 0, stream>>>(Qpre, Qr, pos, NH, 0.08838834764831843f);
    rope_kernel<<<(S_LEN * NKV * 64 + 255) / 256, 256, 0, stream>>>(Kpre, Kr, pos, NKV, 1.0f);
    // 5. V transpose: [S][NKV*128] -> [NKV*128][S] == [NKV][128][S]
    transpose_cast_kernel<<<dim3(1024 / 32, S_LEN / 32), tb, 0, stream>>>(Vpre, Vt, S_LEN, 1024);
    // 6. flash attention
    attn_kernel<<<dim3(S_LEN / 64, NH), 256, 0, stream>>>(Qr, Kr, Vt, Oat);
    // 7. output projection
    gemm_bt_kernel<<<dim3(HIDDEN / 128, S_LEN / 128), 256, 0, stream>>>(Oat, WoT, out, S_LEN, HIDDEN, HIDDEN);
}

// Round 2
// 798.503 us; speedup vs baseline: 1.1366x; 1.1366x over previous
//
#include <hip/hip_runtime.h>
#include <hip/hip_bf16.h>
#include <math.h>

#define S_LEN 2048
#define HIDDEN 4096
#define NH 32
#define NKV 8
#define HD 128
#define NQKV 6144   // NH*HD + 2*NKV*HD

typedef __bf16 bf16_t;
typedef __bf16 bf16x8 __attribute__((ext_vector_type(8)));
typedef __bf16 bf16x4 __attribute__((ext_vector_type(4)));
typedef float f32x4 __attribute__((ext_vector_type(4)));

typedef __attribute__((address_space(1))) void gvoid;
typedef __attribute__((address_space(3))) void lvoid;

__device__ __forceinline__ void gload_lds16(const void* g, void* l) {
    __builtin_amdgcn_global_load_lds((gvoid*)g, (lvoid*)l, 16, 0, 0);
}

// ---------------- cast fp32 -> bf16 (vectorized) ----------------
__global__ void cast_bf16_kernel(const float* __restrict__ in, bf16_t* __restrict__ out, int n4) {
    int stride = gridDim.x * blockDim.x;
    for (int idx = blockIdx.x * blockDim.x + threadIdx.x; idx < n4; idx += stride) {
        float4 v = ((const float4*)in)[idx];
        bf16x4 o;
        o.x = (bf16_t)v.x; o.y = (bf16_t)v.y; o.z = (bf16_t)v.z; o.w = (bf16_t)v.w;
        ((bf16x4*)out)[idx] = o;
    }
}

// ---------------- transpose + cast: in[R][C] (stride ldin) -> out[C][R] (stride ldout), bf16 ----------------
__global__ __launch_bounds__(256) void transpose_cast_kernel(const float* __restrict__ in,
                                                             bf16_t* __restrict__ out,
                                                             int ldin, int ldout) {
    __shared__ float t[32][33];
    int c0 = blockIdx.x * 32, r0 = blockIdx.y * 32;
    int tx = threadIdx.x, ty = threadIdx.y;
#pragma unroll
    for (int i = 0; i < 4; ++i)
        t[ty + i * 8][tx] = in[(size_t)(r0 + ty + i * 8) * ldin + c0 + tx];
    __syncthreads();
#pragma unroll
    for (int i = 0; i < 4; ++i)
        out[(size_t)(c0 + ty + i * 8) * ldout + r0 + tx] = (bf16_t)t[tx][ty + i * 8];
}

// ---------------- GEMM: C[M][N] = A[M][K] @ Bt[N][K]^T, fp32 out ----------------
// 128x128 tile, 4 waves (each 64x64), BK=32, global_load_lds staging.
__global__ __launch_bounds__(256) void gemm_bt_kernel(const bf16_t* __restrict__ A,
                                                      const bf16_t* __restrict__ Bt,
                                                      float* __restrict__ C,
                                                      int M, int N, int K) {
    __shared__ bf16_t As[128 * 32];
    __shared__ bf16_t Bs[128 * 32];
    const int tid = threadIdx.x;
    const int lane = tid & 63, w = tid >> 6;
    const int wr = w >> 1, wc = w & 1;
    const int bm = blockIdx.y, bn = blockIdx.x;
    const int g = lane >> 4, c16 = lane & 15;
    const bf16_t* Ab = A + (size_t)bm * 128 * K;
    const bf16_t* Bb = Bt + (size_t)bn * 128 * K;

    f32x4 acc[4][4];
#pragma unroll
    for (int i = 0; i < 4; ++i)
#pragma unroll
        for (int j = 0; j < 4; ++j)
            acc[i][j] = (f32x4){0.f, 0.f, 0.f, 0.f};

    for (int kt = 0; kt < K; kt += 32) {
#pragma unroll
        for (int is = 0; is < 2; ++is) {
            int e = (is * 256 + tid) * 8;          // element index in 128x32 tile
            int row = e >> 5, col = e & 31;
            gload_lds16(Ab + (size_t)row * K + kt + col, As + (size_t)(is * 256 + w * 64) * 8);
            gload_lds16(Bb + (size_t)row * K + kt + col, Bs + (size_t)(is * 256 + w * 64) * 8);
        }
        __syncthreads();
        bf16x8 a[4], b[4];
#pragma unroll
        for (int mi = 0; mi < 4; ++mi)
            a[mi] = *(const bf16x8*)(As + (wr * 64 + mi * 16 + c16) * 32 + g * 8);
#pragma unroll
        for (int ni = 0; ni < 4; ++ni)
            b[ni] = *(const bf16x8*)(Bs + (wc * 64 + ni * 16 + c16) * 32 + g * 8);
#pragma unroll
        for (int mi = 0; mi < 4; ++mi)
#pragma unroll
            for (int ni = 0; ni < 4; ++ni)
                acc[mi][ni] = __builtin_amdgcn_mfma_f32_16x16x32_bf16(a[mi], b[ni], acc[mi][ni], 0, 0, 0);
        __syncthreads();
    }
#pragma unroll
    for (int mi = 0; mi < 4; ++mi)
#pragma unroll
        for (int ni = 0; ni < 4; ++ni) {
            int col = bn * 128 + wc * 64 + ni * 16 + c16;
#pragma unroll
            for (int r = 0; r < 4; ++r) {
                int row = bm * 128 + wr * 64 + mi * 16 + g * 4 + r;
                C[(size_t)row * N + col] = acc[mi][ni][r];
            }
        }
}

// ---------------- RoPE: in fp32 [S][ld] (head block at col h*128) -> out bf16 [H][S][128] ----------------
__global__ void rope_kernel(const float* __restrict__ in, bf16_t* __restrict__ out,
                            const int* __restrict__ pos, int H, int ld, float scale) {
    int idx = blockIdx.x * blockDim.x + threadIdx.x;
    int total = S_LEN * H * 64;
    if (idx >= total) return;
    int d = idx & 63;
    int h = (idx >> 6) % H;
    int s = idx / (64 * H);
    const float* base = in + (size_t)s * ld + h * HD;
    float x0 = base[d], x1 = base[d + 64];
    float p = (float)pos[s];
    float invf = __expf(-0.14391156831212787f * (float)d);  // ln(10000)/64
    float f = p * invf;
    float sn, cs;
    __sincosf(f, &sn, &cs);
    float o0 = (x0 * cs - x1 * sn) * scale;
    float o1 = (x1 * cs + x0 * sn) * scale;
    bf16_t* ob = out + ((size_t)h * S_LEN + s) * HD;
    ob[d] = (bf16_t)o0;
    ob[d + 64] = (bf16_t)o1;
}

// ---------------- flash attention (wave-independent, KVBLK=64) ----------------
// grid (S/64, NH), block 256 (4 waves). wave w handles 16 q rows, NO cross-wave sync.
// Q bf16 [NH][S][128] (pre-scaled), K bf16 [NKV][S][128], Vt bf16 [NKV][128][S].
// O bf16 [S][NH*128].
#define PLD 72   // P row stride in bf16 elems (pad breaks 128B bank stride)
__global__ __launch_bounds__(256) void attn_kernel(const bf16_t* __restrict__ Q,
                                                   const bf16_t* __restrict__ K,
                                                   const bf16_t* __restrict__ Vt,
                                                   bf16_t* __restrict__ O) {
    __shared__ bf16_t Pl[4][16 * PLD];
    const int tid = threadIdx.x;
    const int lane = tid & 63, w = tid >> 6;
    const int h = blockIdx.y;
    const int kv = h >> 2;               // N_REP = 4
    const int qb = blockIdx.x * 64 + w * 16;
    const int g = lane >> 4, c16 = lane & 15;
    const bf16_t* Qh = Q + (size_t)h * S_LEN * HD;
    const bf16_t* Kh = K + (size_t)kv * S_LEN * HD;
    const bf16_t* Vh = Vt + (size_t)kv * HD * S_LEN;
    bf16_t* P = Pl[w];

    bf16x8 qf[4];
#pragma unroll
    for (int c = 0; c < 4; ++c)
        qf[c] = *(const bf16x8*)(Qh + (size_t)(qb + c16) * HD + c * 32 + g * 8);

    f32x4 acc_o[8];
#pragma unroll
    for (int dt = 0; dt < 8; ++dt) acc_o[dt] = (f32x4){0.f, 0.f, 0.f, 0.f};
    float m[4] = {-1e30f, -1e30f, -1e30f, -1e30f};
    float l[4] = {0.f, 0.f, 0.f, 0.f};

    const int nkt = blockIdx.x + 1;      // KVBLK=64; diagonal tile is last
    for (int kt = 0; kt < nkt; ++kt) {
        const int kb = kt * 64;
        f32x4 sacc[4];
#pragma unroll
        for (int t = 0; t < 4; ++t) sacc[t] = (f32x4){0.f, 0.f, 0.f, 0.f};
#pragma unroll
        for (int t = 0; t < 4; ++t)
#pragma unroll
            for (int c = 0; c < 4; ++c) {
                bf16x8 kf = *(const bf16x8*)(Kh + (size_t)(kb + t * 16 + c16) * HD + c * 32 + g * 8);
                sacc[t] = __builtin_amdgcn_mfma_f32_16x16x32_bf16(qf[c], kf, sacc[t], 0, 0, 0);
            }
        // mask + online softmax: row q = qb + g*4 + r lives across the 16 lanes c16
        float p[4][4], alpha[4];
#pragma unroll
        for (int r = 0; r < 4; ++r) {
            int qq = qb + g * 4 + r;
            float s[4];
#pragma unroll
            for (int t = 0; t < 4; ++t)
                s[t] = (kb + t * 16 + c16 <= qq) ? sacc[t][r] : -1e30f;
            float mx = fmaxf(fmaxf(s[0], s[1]), fmaxf(s[2], s[3]));
            mx = fmaxf(mx, __shfl_xor(mx, 1));
            mx = fmaxf(mx, __shfl_xor(mx, 2));
            mx = fmaxf(mx, __shfl_xor(mx, 4));
            mx = fmaxf(mx, __shfl_xor(mx, 8));
            float mn = fmaxf(m[r], mx);
            alpha[r] = __expf(m[r] - mn);
            m[r] = mn;
            float rs = 0.f;
#pragma unroll
            for (int t = 0; t < 4; ++t) {
                p[t][r] = __expf(s[t] - mn);
                rs += p[t][r];
            }
            rs += __shfl_xor(rs, 1);
            rs += __shfl_xor(rs, 2);
            rs += __shfl_xor(rs, 4);
            rs += __shfl_xor(rs, 8);
            l[r] = l[r] * alpha[r] + rs;
        }
#pragma unroll
        for (int dt = 0; dt < 8; ++dt)
#pragma unroll
            for (int r = 0; r < 4; ++r) acc_o[dt][r] *= alpha[r];
        // P -> LDS (C-layout to A-layout redistribution), per-wave buffer: no barrier needed
#pragma unroll
        for (int t = 0; t < 4; ++t)
#pragma unroll
            for (int r = 0; r < 4; ++r)
                P[(g * 4 + r) * PLD + t * 16 + c16] = (bf16_t)p[t][r];
        bf16x8 pf[2];
        pf[0] = *(const bf16x8*)(P + c16 * PLD + g * 8);
        pf[1] = *(const bf16x8*)(P + c16 * PLD + 32 + g * 8);
#pragma unroll
        for (int dt = 0; dt < 8; ++dt) {
            const bf16_t* vrow = Vh + (size_t)(dt * 16 + c16) * S_LEN + kb;
            bf16x8 vf0 = *(const bf16x8*)(vrow + g * 8);
            bf16x8 vf1 = *(const bf16x8*)(vrow + 32 + g * 8);
            acc_o[dt] = __builtin_amdgcn_mfma_f32_16x16x32_bf16(pf[0], vf0, acc_o[dt], 0, 0, 0);
            acc_o[dt] = __builtin_amdgcn_mfma_f32_16x16x32_bf16(pf[1], vf1, acc_o[dt], 0, 0, 0);
        }
    }
    float inv_l[4];
#pragma unroll
    for (int r = 0; r < 4; ++r) inv_l[r] = 1.f / l[r];
#pragma unroll
    for (int dt = 0; dt < 8; ++dt)
#pragma unroll
        for (int r = 0; r < 4; ++r)
            O[(size_t)(qb + g * 4 + r) * HIDDEN + h * HD + dt * 16 + c16] =
                (bf16_t)(acc_o[dt][r] * inv_l[r]);
}

// ---------------- host ----------------
extern "C" void kernel_launch(void* const* d_in, const int* in_sizes, int n_in,
                              void* d_out, int out_size, void* d_ws, size_t ws_size,
                              hipStream_t stream) {
    const float* hs = (const float*)d_in[0];
    const float* Wq = (const float*)d_in[1];
    const float* Wk = (const float*)d_in[2];
    const float* Wv = (const float*)d_in[3];
    const float* Wo = (const float*)d_in[4];
    const int* pos = (const int*)d_in[6];
    float* out = (float*)d_out;

    char* ws = (char*)d_ws;
    size_t off = 0;
    auto alloc = [&](size_t bytes) -> void* {
        void* p = ws + off;
        off += (bytes + 255) & ~(size_t)255;
        return p;
    };
    bf16_t* hB    = (bf16_t*)alloc((size_t)S_LEN * HIDDEN * 2);
    bf16_t* WqkvT = (bf16_t*)alloc((size_t)NQKV * HIDDEN * 2);   // [6144][4096]
    bf16_t* WoT   = (bf16_t*)alloc((size_t)HIDDEN * HIDDEN * 2);
    float*  QKV   = (float*)alloc((size_t)S_LEN * NQKV * 4);     // [2048][6144]
    bf16_t* Qr    = (bf16_t*)alloc((size_t)NH * S_LEN * HD * 2);
    bf16_t* Kr    = (bf16_t*)alloc((size_t)NKV * S_LEN * HD * 2);
    bf16_t* Vt    = (bf16_t*)alloc((size_t)NKV * HD * S_LEN * 2);
    bf16_t* Oat   = (bf16_t*)alloc((size_t)S_LEN * HIDDEN * 2);

    dim3 tb(32, 8);
    // 1. cast hidden to bf16
    cast_bf16_kernel<<<2048, 256, 0, stream>>>(hs, hB, S_LEN * HIDDEN / 4);
    // 2. transpose-cast weights into fused [6144][4096] (Q rows 0..4095, K 4096..5119, V 5120..6143)
    transpose_cast_kernel<<<dim3(HIDDEN / 32, HIDDEN / 32), tb, 0, stream>>>(Wq, WqkvT, HIDDEN, HIDDEN);
    transpose_cast_kernel<<<dim3(1024 / 32, HIDDEN / 32), tb, 0, stream>>>(Wk, WqkvT + (size_t)4096 * HIDDEN, 1024, HIDDEN);
    transpose_cast_kernel<<<dim3(1024 / 32, HIDDEN / 32), tb, 0, stream>>>(Wv, WqkvT + (size_t)5120 * HIDDEN, 1024, HIDDEN);
    transpose_cast_kernel<<<dim3(HIDDEN / 32, HIDDEN / 32), tb, 0, stream>>>(Wo, WoT, HIDDEN, HIDDEN);
    // 3. fused QKV projection: [2048][4096] @ [4096][6144] -> [2048][6144]
    gemm_bt_kernel<<<dim3(NQKV / 128, S_LEN / 128), 256, 0, stream>>>(hB, WqkvT, QKV, S_LEN, NQKV, HIDDEN);
    // 4. RoPE (fold 1/sqrt(128) into Q)
    rope_kernel<<<(S_LEN * NH * 64 + 255) / 256, 256, 0, stream>>>(QKV, Qr, pos, NH, NQKV, 0.08838834764831843f);
    rope_kernel<<<(S_LEN * NKV * 64 + 255) / 256, 256, 0, stream>>>(QKV + 4096, Kr, pos, NKV, NQKV, 1.0f);
    // 5. V transpose: [S][1024] (stride 6144) -> [1024][2048] == [NKV][128][S]
    transpose_cast_kernel<<<dim3(1024 / 32, S_LEN / 32), tb, 0, stream>>>(QKV + 5120, Vt, NQKV, S_LEN);
    // 6. flash attention
    attn_kernel<<<dim3(S_LEN / 64, NH), 256, 0, stream>>>(Qr, Kr, Vt, Oat);
    // 7. output projection
    gemm_bt_kernel<<<dim3(HIDDEN / 128, S_LEN / 128), 256, 0, stream>>>(Oat, WoT, out, S_LEN, HIDDEN, HIDDEN);
}

// Round 3
// 441.825 us; speedup vs baseline: 2.0541x; 1.8073x over previous
//
#include <hip/hip_runtime.h>
#include <hip/hip_bf16.h>
#include <math.h>

#define S_LEN 2048
#define HIDDEN 4096
#define NH 32
#define NKV 8
#define HD 128
#define NQKV 6144   // NH*HD + 2*NKV*HD

typedef __bf16 bf16_t;
typedef __bf16 bf16x8 __attribute__((ext_vector_type(8)));
typedef __bf16 bf16x4 __attribute__((ext_vector_type(4)));
typedef float f32x4 __attribute__((ext_vector_type(4)));

typedef __attribute__((address_space(1))) void gvoid;
typedef __attribute__((address_space(3))) void lvoid;

__device__ __forceinline__ void gload_lds16(const void* g, void* l) {
    __builtin_amdgcn_global_load_lds((gvoid*)g, (lvoid*)l, 16, 0, 0);
}

// ---------------- cast fp32 -> bf16 (vectorized) ----------------
__global__ void cast_bf16_kernel(const float* __restrict__ in, bf16_t* __restrict__ out, int n4) {
    int stride = gridDim.x * blockDim.x;
    for (int idx = blockIdx.x * blockDim.x + threadIdx.x; idx < n4; idx += stride) {
        float4 v = ((const float4*)in)[idx];
        bf16x4 o;
        o.x = (bf16_t)v.x; o.y = (bf16_t)v.y; o.z = (bf16_t)v.z; o.w = (bf16_t)v.w;
        ((bf16x4*)out)[idx] = o;
    }
}

// ---------------- transpose + cast: in[R][C] (stride ldin) -> out[C][R] (stride ldout), bf16 ----------------
__global__ __launch_bounds__(256) void transpose_cast_kernel(const float* __restrict__ in,
                                                             bf16_t* __restrict__ out,
                                                             int ldin, int ldout) {
    __shared__ float t[32][33];
    int c0 = blockIdx.x * 32, r0 = blockIdx.y * 32;
    int tx = threadIdx.x, ty = threadIdx.y;
#pragma unroll
    for (int i = 0; i < 4; ++i)
        t[ty + i * 8][tx] = in[(size_t)(r0 + ty + i * 8) * ldin + c0 + tx];
    __syncthreads();
#pragma unroll
    for (int i = 0; i < 4; ++i)
        out[(size_t)(c0 + ty + i * 8) * ldout + r0 + tx] = (bf16_t)t[tx][ty + i * 8];
}

// ---------------- GEMM: C[M][N] = A[M][K] @ Bt[N][K]^T, fp32 out ----------------
__global__ __launch_bounds__(256) void gemm_bt_kernel(const bf16_t* __restrict__ A,
                                                      const bf16_t* __restrict__ Bt,
                                                      float* __restrict__ C,
                                                      int M, int N, int K) {
    __shared__ bf16_t As[128 * 32];
    __shared__ bf16_t Bs[128 * 32];
    const int tid = threadIdx.x;
    const int lane = tid & 63, w = tid >> 6;
    const int wr = w >> 1, wc = w & 1;
    const int bm = blockIdx.y, bn = blockIdx.x;
    const int g = lane >> 4, c16 = lane & 15;
    const bf16_t* Ab = A + (size_t)bm * 128 * K;
    const bf16_t* Bb = Bt + (size_t)bn * 128 * K;

    f32x4 acc[4][4];
#pragma unroll
    for (int i = 0; i < 4; ++i)
#pragma unroll
        for (int j = 0; j < 4; ++j)
            acc[i][j] = (f32x4){0.f, 0.f, 0.f, 0.f};

    for (int kt = 0; kt < K; kt += 32) {
#pragma unroll
        for (int is = 0; is < 2; ++is) {
            int e = (is * 256 + tid) * 8;          // element index in 128x32 tile
            int row = e >> 5, col = e & 31;
            gload_lds16(Ab + (size_t)row * K + kt + col, As + (size_t)(is * 256 + w * 64) * 8);
            gload_lds16(Bb + (size_t)row * K + kt + col, Bs + (size_t)(is * 256 + w * 64) * 8);
        }
        __syncthreads();
        bf16x8 a[4], b[4];
#pragma unroll
        for (int mi = 0; mi < 4; ++mi)
            a[mi] = *(const bf16x8*)(As + (wr * 64 + mi * 16 + c16) * 32 + g * 8);
#pragma unroll
        for (int ni = 0; ni < 4; ++ni)
            b[ni] = *(const bf16x8*)(Bs + (wc * 64 + ni * 16 + c16) * 32 + g * 8);
#pragma unroll
        for (int mi = 0; mi < 4; ++mi)
#pragma unroll
            for (int ni = 0; ni < 4; ++ni)
                acc[mi][ni] = __builtin_amdgcn_mfma_f32_16x16x32_bf16(a[mi], b[ni], acc[mi][ni], 0, 0, 0);
        __syncthreads();
    }
#pragma unroll
    for (int mi = 0; mi < 4; ++mi)
#pragma unroll
        for (int ni = 0; ni < 4; ++ni) {
            int col = bn * 128 + wc * 64 + ni * 16 + c16;
#pragma unroll
            for (int r = 0; r < 4; ++r) {
                int row = bm * 128 + wr * 64 + mi * 16 + g * 4 + r;
                C[(size_t)row * N + col] = acc[mi][ni][r];
            }
        }
}

// ---------------- RoPE: in fp32 [S][ld] (head block at col h*128) -> out bf16 [H][S][128] ----------------
__global__ void rope_kernel(const float* __restrict__ in, bf16_t* __restrict__ out,
                            const int* __restrict__ pos, int H, int ld, float scale) {
    int idx = blockIdx.x * blockDim.x + threadIdx.x;
    int total = S_LEN * H * 64;
    if (idx >= total) return;
    int d = idx & 63;
    int h = (idx >> 6) % H;
    int s = idx / (64 * H);
    const float* base = in + (size_t)s * ld + h * HD;
    float x0 = base[d], x1 = base[d + 64];
    float p = (float)pos[s];
    float invf = __expf(-0.14391156831212787f * (float)d);  // ln(10000)/64
    float f = p * invf;
    float sn, cs;
    __sincosf(f, &sn, &cs);
    float o0 = (x0 * cs - x1 * sn) * scale;
    float o1 = (x1 * cs + x0 * sn) * scale;
    bf16_t* ob = out + ((size_t)h * S_LEN + s) * HD;
    ob[d] = (bf16_t)o0;
    ob[d + 64] = (bf16_t)o1;
}

// ---------------- flash attention (cooperative LDS staging, 2-phase pipeline) ----------------
// grid 1024 blocks (bid: h = bid&31 fastest for CU load balance, x = bid>>5), block 256 (4 waves).
// Wave w owns q rows qb..qb+15. All 4 waves share K/V tiles staged in LDS (double-buffered,
// global_load_lds w/ XOR-swizzle: linear LDS dest + inverse-swizzled global source + swizzled read).
// Q bf16 [NH][S][128] (pre-scaled), K bf16 [NKV][S][128], Vt bf16 [NKV][128][S]. O bf16 [S][NH*128].
#define PLD 72
__global__ __launch_bounds__(256) void attn_kernel(const bf16_t* __restrict__ Q,
                                                   const bf16_t* __restrict__ K,
                                                   const bf16_t* __restrict__ Vt,
                                                   bf16_t* __restrict__ O) {
    __shared__ bf16_t Ks[2][64 * 128];   // [kv row][d], swizzled chunks
    __shared__ bf16_t Vs[2][128 * 64];   // [d][kv], swizzled chunks
    __shared__ bf16_t Pl[4][16 * PLD];
    const int tid = threadIdx.x;
    const int lane = tid & 63, w = tid >> 6;
    const int bid = blockIdx.x;
    const int h = bid & 31;
    const int x = bid >> 5;
    const int kv = h >> 2;               // N_REP = 4
    const int qb = x * 64 + w * 16;
    const int g = lane >> 4, c16 = lane & 15;
    const int c7 = c16 & 7;
    const bf16_t* Qh = Q + (size_t)h * S_LEN * HD;
    const bf16_t* Kh = K + (size_t)kv * S_LEN * HD;
    const bf16_t* Vh = Vt + (size_t)kv * HD * S_LEN;
    bf16_t* P = Pl[w];

    // stage K (64x128) + V (128x64) tile at kv offset kb into buffer buf.
    // 16 gload_lds x 1KB each per matrix; wave w issues instrs i = 4w..4w+3.
    auto stage = [&](int buf, int kb) {
        bf16_t* Kd = Ks[buf];
        bf16_t* Vd = Vs[buf];
#pragma unroll
        for (int j = 0; j < 4; ++j) {
            int i = w * 4 + j;
            {   // K: instr covers 4 rows of 256B; lane l -> row 4i+(l>>4), chunk l&15
                int row = 4 * i + (lane >> 4);
                int sc = (lane & 15) ^ (row & 7);
                gload_lds16(Kh + (size_t)(kb + row) * HD + sc * 8, Kd + i * 512);
            }
            {   // V: instr covers 8 rows of 128B; lane l -> row 8i+(l>>3), chunk l&7
                int row = 8 * i + (lane >> 3);
                int sc = (lane & 7) ^ ((lane >> 3) & 7);
                gload_lds16(Vh + (size_t)row * S_LEN + kb + sc * 8, Vd + i * 512);
            }
        }
    };

    bf16x8 qf[4];
#pragma unroll
    for (int c = 0; c < 4; ++c)
        qf[c] = *(const bf16x8*)(Qh + (size_t)(qb + c16) * HD + c * 32 + g * 8);

    f32x4 acc_o[8];
#pragma unroll
    for (int dt = 0; dt < 8; ++dt) acc_o[dt] = (f32x4){0.f, 0.f, 0.f, 0.f};
    float m[4] = {-1e30f, -1e30f, -1e30f, -1e30f};
    float l[4] = {0.f, 0.f, 0.f, 0.f};

    const int nkt = x + 1;               // KVBLK=64; diagonal tile is last
    stage(0, 0);
    __syncthreads();                     // drains vmcnt before barrier (compiler-emitted)
    int cur = 0;

    for (int kt = 0; kt < nkt; ++kt) {
        if (kt + 1 < nkt) stage(cur ^ 1, (kt + 1) * 64);
        const int kb = kt * 64;
        const bf16_t* Kb = Ks[cur];
        const bf16_t* Vb = Vs[cur];
        const bool diag = (kt == nkt - 1);

        f32x4 sacc[4];
#pragma unroll
        for (int t = 0; t < 4; ++t) sacc[t] = (f32x4){0.f, 0.f, 0.f, 0.f};
#pragma unroll
        for (int t = 0; t < 4; ++t) {
            const bf16_t* krow = Kb + (t * 16 + c16) * 128;
#pragma unroll
            for (int cc = 0; cc < 4; ++cc) {
                bf16x8 kf = *(const bf16x8*)(krow + (((cc * 4 + g) ^ c7) * 8));
                sacc[t] = __builtin_amdgcn_mfma_f32_16x16x32_bf16(qf[cc], kf, sacc[t], 0, 0, 0);
            }
        }
        // mask + online softmax: row q = qb + g*4 + r lives across the 16 lanes c16
        float p[4][4], alpha[4];
#pragma unroll
        for (int r = 0; r < 4; ++r) {
            int qq = qb + g * 4 + r;
            float s[4];
#pragma unroll
            for (int t = 0; t < 4; ++t)
                s[t] = (!diag || (kb + t * 16 + c16 <= qq)) ? sacc[t][r] : -1e30f;
            float mx = fmaxf(fmaxf(s[0], s[1]), fmaxf(s[2], s[3]));
            mx = fmaxf(mx, __shfl_xor(mx, 1));
            mx = fmaxf(mx, __shfl_xor(mx, 2));
            mx = fmaxf(mx, __shfl_xor(mx, 4));
            mx = fmaxf(mx, __shfl_xor(mx, 8));
            float mn = fmaxf(m[r], mx);
            alpha[r] = __expf(m[r] - mn);
            m[r] = mn;
            float rs = 0.f;
#pragma unroll
            for (int t = 0; t < 4; ++t) {
                p[t][r] = __expf(s[t] - mn);
                rs += p[t][r];
            }
            rs += __shfl_xor(rs, 1);
            rs += __shfl_xor(rs, 2);
            rs += __shfl_xor(rs, 4);
            rs += __shfl_xor(rs, 8);
            l[r] = l[r] * alpha[r] + rs;
        }
#pragma unroll
        for (int dt = 0; dt < 8; ++dt)
#pragma unroll
            for (int r = 0; r < 4; ++r) acc_o[dt][r] *= alpha[r];
        // P -> LDS (C-layout to A-layout redistribution), per-wave buffer: in-wave dep only
#pragma unroll
        for (int t = 0; t < 4; ++t)
#pragma unroll
            for (int r = 0; r < 4; ++r)
                P[(g * 4 + r) * PLD + t * 16 + c16] = (bf16_t)p[t][r];
        bf16x8 pf[2];
        pf[0] = *(const bf16x8*)(P + c16 * PLD + g * 8);
        pf[1] = *(const bf16x8*)(P + c16 * PLD + 32 + g * 8);
#pragma unroll
        for (int dt = 0; dt < 8; ++dt) {
            const bf16_t* vrow = Vb + (dt * 16 + c16) * 64;
            bf16x8 vf0 = *(const bf16x8*)(vrow + ((g ^ c7) * 8));
            bf16x8 vf1 = *(const bf16x8*)(vrow + (((4 + g) ^ c7) * 8));
            acc_o[dt] = __builtin_amdgcn_mfma_f32_16x16x32_bf16(pf[0], vf0, acc_o[dt], 0, 0, 0);
            acc_o[dt] = __builtin_amdgcn_mfma_f32_16x16x32_bf16(pf[1], vf1, acc_o[dt], 0, 0, 0);
        }
        __syncthreads();                 // stage(next) complete + everyone done reading cur
        cur ^= 1;
    }
    float inv_l[4];
#pragma unroll
    for (int r = 0; r < 4; ++r) inv_l[r] = 1.f / l[r];
#pragma unroll
    for (int dt = 0; dt < 8; ++dt)
#pragma unroll
        for (int r = 0; r < 4; ++r)
            O[(size_t)(qb + g * 4 + r) * HIDDEN + h * HD + dt * 16 + c16] =
                (bf16_t)(acc_o[dt][r] * inv_l[r]);
}

// ---------------- host ----------------
extern "C" void kernel_launch(void* const* d_in, const int* in_sizes, int n_in,
                              void* d_out, int out_size, void* d_ws, size_t ws_size,
                              hipStream_t stream) {
    const float* hs = (const float*)d_in[0];
    const float* Wq = (const float*)d_in[1];
    const float* Wk = (const float*)d_in[2];
    const float* Wv = (const float*)d_in[3];
    const float* Wo = (const float*)d_in[4];
    const int* pos = (const int*)d_in[6];
    float* out = (float*)d_out;

    char* ws = (char*)d_ws;
    size_t off = 0;
    auto alloc = [&](size_t bytes) -> void* {
        void* p = ws + off;
        off += (bytes + 255) & ~(size_t)255;
        return p;
    };
    bf16_t* hB    = (bf16_t*)alloc((size_t)S_LEN * HIDDEN * 2);
    bf16_t* WqkvT = (bf16_t*)alloc((size_t)NQKV * HIDDEN * 2);   // [6144][4096]
    bf16_t* WoT   = (bf16_t*)alloc((size_t)HIDDEN * HIDDEN * 2);
    float*  QKV   = (float*)alloc((size_t)S_LEN * NQKV * 4);     // [2048][6144]
    bf16_t* Qr    = (bf16_t*)alloc((size_t)NH * S_LEN * HD * 2);
    bf16_t* Kr    = (bf16_t*)alloc((size_t)NKV * S_LEN * HD * 2);
    bf16_t* Vt    = (bf16_t*)alloc((size_t)NKV * HD * S_LEN * 2);
    bf16_t* Oat   = (bf16_t*)alloc((size_t)S_LEN * HIDDEN * 2);

    dim3 tb(32, 8);
    // 1. cast hidden to bf16
    cast_bf16_kernel<<<2048, 256, 0, stream>>>(hs, hB, S_LEN * HIDDEN / 4);
    // 2. transpose-cast weights into fused [6144][4096] (Q rows 0..4095, K 4096..5119, V 5120..6143)
    transpose_cast_kernel<<<dim3(HIDDEN / 32, HIDDEN / 32), tb, 0, stream>>>(Wq, WqkvT, HIDDEN, HIDDEN);
    transpose_cast_kernel<<<dim3(1024 / 32, HIDDEN / 32), tb, 0, stream>>>(Wk, WqkvT + (size_t)4096 * HIDDEN, 1024, HIDDEN);
    transpose_cast_kernel<<<dim3(1024 / 32, HIDDEN / 32), tb, 0, stream>>>(Wv, WqkvT + (size_t)5120 * HIDDEN, 1024, HIDDEN);
    transpose_cast_kernel<<<dim3(HIDDEN / 32, HIDDEN / 32), tb, 0, stream>>>(Wo, WoT, HIDDEN, HIDDEN);
    // 3. fused QKV projection: [2048][4096] @ [4096][6144] -> [2048][6144]
    gemm_bt_kernel<<<dim3(NQKV / 128, S_LEN / 128), 256, 0, stream>>>(hB, WqkvT, QKV, S_LEN, NQKV, HIDDEN);
    // 4. RoPE (fold 1/sqrt(128) into Q)
    rope_kernel<<<(S_LEN * NH * 64 + 255) / 256, 256, 0, stream>>>(QKV, Qr, pos, NH, NQKV, 0.08838834764831843f);
    rope_kernel<<<(S_LEN * NKV * 64 + 255) / 256, 256, 0, stream>>>(QKV + 4096, Kr, pos, NKV, NQKV, 1.0f);
    // 5. V transpose: [S][1024] (stride 6144) -> [1024][2048] == [NKV][128][S]
    transpose_cast_kernel<<<dim3(1024 / 32, S_LEN / 32), tb, 0, stream>>>(QKV + 5120, Vt, NQKV, S_LEN);
    // 6. flash attention
    attn_kernel<<<1024, 256, 0, stream>>>(Qr, Kr, Vt, Oat);
    // 7. output projection
    gemm_bt_kernel<<<dim3(HIDDEN / 128, S_LEN / 128), 256, 0, stream>>>(Oat, WoT, out, S_LEN, HIDDEN, HIDDEN);
}

// Round 4
// 434.999 us; speedup vs baseline: 2.0864x; 1.0157x over previous
//
#include <hip/hip_runtime.h>
#include <hip/hip_bf16.h>
#include <math.h>

#define S_LEN 2048
#define HIDDEN 4096
#define NH 32
#define NKV 8
#define HD 128
#define NQKV 6144   // NH*HD + 2*NKV*HD

typedef __bf16 bf16_t;
typedef __bf16 bf16x8 __attribute__((ext_vector_type(8)));
typedef __bf16 bf16x4 __attribute__((ext_vector_type(4)));
typedef float f32x4 __attribute__((ext_vector_type(4)));

typedef __attribute__((address_space(1))) void gvoid;
typedef __attribute__((address_space(3))) void lvoid;

__device__ __forceinline__ void gload_lds16(const void* g, void* l) {
    __builtin_amdgcn_global_load_lds((gvoid*)g, (lvoid*)l, 16, 0, 0);
}

// ---------------- cast fp32 -> bf16 (vectorized) ----------------
__global__ void cast_bf16_kernel(const float* __restrict__ in, bf16_t* __restrict__ out, int n4) {
    int stride = gridDim.x * blockDim.x;
    for (int idx = blockIdx.x * blockDim.x + threadIdx.x; idx < n4; idx += stride) {
        float4 v = ((const float4*)in)[idx];
        bf16x4 o;
        o.x = (bf16_t)v.x; o.y = (bf16_t)v.y; o.z = (bf16_t)v.z; o.w = (bf16_t)v.w;
        ((bf16x4*)out)[idx] = o;
    }
}

// ---------------- transpose + cast: in[R][C] (stride ldin) -> out[C][R] (stride ldout), bf16 ----------------
__global__ __launch_bounds__(256) void transpose_cast_kernel(const float* __restrict__ in,
                                                             bf16_t* __restrict__ out,
                                                             int ldin, int ldout) {
    __shared__ float t[32][33];
    int c0 = blockIdx.x * 32, r0 = blockIdx.y * 32;
    int tx = threadIdx.x, ty = threadIdx.y;
#pragma unroll
    for (int i = 0; i < 4; ++i)
        t[ty + i * 8][tx] = in[(size_t)(r0 + ty + i * 8) * ldin + c0 + tx];
    __syncthreads();
#pragma unroll
    for (int i = 0; i < 4; ++i)
        out[(size_t)(c0 + ty + i * 8) * ldout + r0 + tx] = (bf16_t)t[tx][ty + i * 8];
}

// ---------------- 8-phase GEMM: C[M][N] = A[M][K] @ Bt[N][K]^T, fp32 out ----------------
// BMxBN tile, BK=64, 8 waves (2M x 4N), per-wave (BM/2)x(BN/4). Double-buffered LDS.
// Pipeline: issue all tile-(t+1) global_load_lds right after tile-t's start barrier
// (dest buffer was last read by tile t-1, which completed before this barrier -> race-free);
// drain vmcnt(0) at tile start => one full tile of compute overlaps the loads.
// G4 XOR swizzle (16B chunk ^= row&7): linear LDS dest + inverse-swizzled global src +
// swizzled ds_read (rule #21). Raw s_barrier phase rhythm + setprio around MFMA (T5).
template<int BM, int BN>
__global__ __launch_bounds__(512, 2) void gemm8p_kernel(const bf16_t* __restrict__ A,
                                                        const bf16_t* __restrict__ Bt,
                                                        float* __restrict__ C,
                                                        int M, int N, int K) {
    constexpr int BK = 64;
    constexpr int M_REP = BM / 32;     // per-wave m fragments
    constexpr int N_REP = BN / 64;     // per-wave n fragments
    constexpr int MH = M_REP / 2;      // m fragments per phase
    constexpr int NA = BM / 64;        // A gload instrs per thread per tile
    constexpr int NB = BN / 64;        // B gload instrs per thread per tile
    __shared__ bf16_t As[2][BM * BK];
    __shared__ bf16_t Bs[2][BN * BK];

    const int tid = threadIdx.x;
    const int lane = tid & 63, wid = tid >> 6;
    const int wm = wid >> 2, wn = wid & 3;
    const int g = lane >> 4, c16 = lane & 15;

    // XCD-aware swizzle (grid % 8 == 0 guaranteed by launch)
    const int nbn = N / BN;
    const int cpx = gridDim.x >> 3;
    const int bid = blockIdx.x;
    const int swz = (bid & 7) * cpx + (bid >> 3);
    const int bn = swz % nbn, bm = swz / nbn;

    const bf16_t* Ab = A + (size_t)(bm * BM) * K;
    const bf16_t* Bb = Bt + (size_t)(bn * BN) * K;

    // staging lane geometry: within an instr, lane -> row += lane>>3, global chunk = (lane&7)^(row&7)
    const int srow = lane >> 3;
    const int scg = (lane & 7) ^ (srow & 7);

    auto stage = [&](int buf, int kt) {
        const bf16_t* Ak = Ab + kt * BK;
        const bf16_t* Bk = Bb + kt * BK;
#pragma unroll
        for (int j = 0; j < NA; ++j) {   // wave stages the A rows it will read (4 waves share wm)
            int rs = wm * (BM / 2) + wn * (BM / 8) + j * 8;
            gload_lds16(Ak + (size_t)(rs + srow) * K + scg * 8, &As[buf][rs * BK]);
        }
#pragma unroll
        for (int j = 0; j < NB; ++j) {   // wave stages the B rows it will read (2 waves share wn)
            int rs = wn * (BN / 4) + wm * (BN / 8) + j * 8;
            gload_lds16(Bk + (size_t)(rs + srow) * K + scg * 8, &Bs[buf][rs * BK]);
        }
    };

    f32x4 acc[M_REP][N_REP];
#pragma unroll
    for (int i = 0; i < M_REP; ++i)
#pragma unroll
        for (int j = 0; j < N_REP; ++j)
            acc[i][j] = (f32x4){0.f, 0.f, 0.f, 0.f};

    const int NT = K / BK;
    stage(0, 0);

    for (int t = 0; t < NT; ++t) {
        const int buf = t & 1;
        asm volatile("s_waitcnt vmcnt(0)" ::: "memory");   // tile t landed (overlapped by tile t-1 compute)
        __builtin_amdgcn_s_barrier();                      // all waves' slices visible
        if (t + 1 < NT) stage(buf ^ 1, t + 1);             // issue next tile ASAP

        bf16x8 bfr[N_REP];
#pragma unroll
        for (int kk = 0; kk < 2; ++kk) {
#pragma unroll
            for (int mh = 0; mh < 2; ++mh) {
                bf16x8 afr[MH];
                if (mh == 0) {
#pragma unroll
                    for (int ni = 0; ni < N_REP; ++ni) {
                        int row = wn * (BN / 4) + ni * 16 + c16;
                        int Ci = kk * 4 + g;
                        bfr[ni] = *(const bf16x8*)(&Bs[buf][row * BK + ((Ci ^ (row & 7)) * 8)]);
                    }
                }
#pragma unroll
                for (int i = 0; i < MH; ++i) {
                    int row = wm * (BM / 2) + (mh * MH + i) * 16 + c16;
                    int Ci = kk * 4 + g;
                    afr[i] = *(const bf16x8*)(&As[buf][row * BK + ((Ci ^ (row & 7)) * 8)]);
                }
                asm volatile("s_waitcnt lgkmcnt(0)" ::: "memory");
                __builtin_amdgcn_sched_barrier(0);
                __builtin_amdgcn_s_setprio(1);
#pragma unroll
                for (int i = 0; i < MH; ++i)
#pragma unroll
                    for (int ni = 0; ni < N_REP; ++ni)
                        acc[mh * MH + i][ni] =
                            __builtin_amdgcn_mfma_f32_16x16x32_bf16(afr[i], bfr[ni], acc[mh * MH + i][ni], 0, 0, 0);
                __builtin_amdgcn_s_setprio(0);
                __builtin_amdgcn_s_barrier();
            }
        }
    }

#pragma unroll
    for (int mi = 0; mi < M_REP; ++mi)
#pragma unroll
        for (int ni = 0; ni < N_REP; ++ni) {
            int col = bn * BN + wn * (BN / 4) + ni * 16 + c16;
#pragma unroll
            for (int r = 0; r < 4; ++r) {
                int row = bm * BM + wm * (BM / 2) + mi * 16 + g * 4 + r;
                C[(size_t)row * N + col] = acc[mi][ni][r];
            }
        }
}

// ---------------- RoPE: in fp32 [S][ld] (head block at col h*128) -> out bf16 [H][S][128] ----------------
__global__ void rope_kernel(const float* __restrict__ in, bf16_t* __restrict__ out,
                            const int* __restrict__ pos, int H, int ld, float scale) {
    int idx = blockIdx.x * blockDim.x + threadIdx.x;
    int total = S_LEN * H * 64;
    if (idx >= total) return;
    int d = idx & 63;
    int h = (idx >> 6) % H;
    int s = idx / (64 * H);
    const float* base = in + (size_t)s * ld + h * HD;
    float x0 = base[d], x1 = base[d + 64];
    float p = (float)pos[s];
    float invf = __expf(-0.14391156831212787f * (float)d);  // ln(10000)/64
    float f = p * invf;
    float sn, cs;
    __sincosf(f, &sn, &cs);
    float o0 = (x0 * cs - x1 * sn) * scale;
    float o1 = (x1 * cs + x0 * sn) * scale;
    bf16_t* ob = out + ((size_t)h * S_LEN + s) * HD;
    ob[d] = (bf16_t)o0;
    ob[d + 64] = (bf16_t)o1;
}

// ---------------- flash attention (cooperative LDS staging, 2-phase pipeline) ----------------
#define PLD 72
__global__ __launch_bounds__(256) void attn_kernel(const bf16_t* __restrict__ Q,
                                                   const bf16_t* __restrict__ K,
                                                   const bf16_t* __restrict__ Vt,
                                                   bf16_t* __restrict__ O) {
    __shared__ bf16_t Ks[2][64 * 128];   // [kv row][d], swizzled chunks
    __shared__ bf16_t Vs[2][128 * 64];   // [d][kv], swizzled chunks
    __shared__ bf16_t Pl[4][16 * PLD];
    const int tid = threadIdx.x;
    const int lane = tid & 63, w = tid >> 6;
    const int bid = blockIdx.x;
    const int h = bid & 31;
    const int x = bid >> 5;
    const int kv = h >> 2;               // N_REP = 4
    const int qb = x * 64 + w * 16;
    const int g = lane >> 4, c16 = lane & 15;
    const int c7 = c16 & 7;
    const bf16_t* Qh = Q + (size_t)h * S_LEN * HD;
    const bf16_t* Kh = K + (size_t)kv * S_LEN * HD;
    const bf16_t* Vh = Vt + (size_t)kv * HD * S_LEN;
    bf16_t* P = Pl[w];

    auto stage = [&](int buf, int kb) {
        bf16_t* Kd = Ks[buf];
        bf16_t* Vd = Vs[buf];
#pragma unroll
        for (int j = 0; j < 4; ++j) {
            int i = w * 4 + j;
            {   // K: instr covers 4 rows of 256B; lane l -> row 4i+(l>>4), chunk l&15
                int row = 4 * i + (lane >> 4);
                int sc = (lane & 15) ^ (row & 7);
                gload_lds16(Kh + (size_t)(kb + row) * HD + sc * 8, Kd + i * 512);
            }
            {   // V: instr covers 8 rows of 128B; lane l -> row 8i+(l>>3), chunk l&7
                int row = 8 * i + (lane >> 3);
                int sc = (lane & 7) ^ ((lane >> 3) & 7);
                gload_lds16(Vh + (size_t)row * S_LEN + kb + sc * 8, Vd + i * 512);
            }
        }
    };

    bf16x8 qf[4];
#pragma unroll
    for (int c = 0; c < 4; ++c)
        qf[c] = *(const bf16x8*)(Qh + (size_t)(qb + c16) * HD + c * 32 + g * 8);

    f32x4 acc_o[8];
#pragma unroll
    for (int dt = 0; dt < 8; ++dt) acc_o[dt] = (f32x4){0.f, 0.f, 0.f, 0.f};
    float m[4] = {-1e30f, -1e30f, -1e30f, -1e30f};
    float l[4] = {0.f, 0.f, 0.f, 0.f};

    const int nkt = x + 1;               // KVBLK=64; diagonal tile is last
    stage(0, 0);
    __syncthreads();
    int cur = 0;

    for (int kt = 0; kt < nkt; ++kt) {
        if (kt + 1 < nkt) stage(cur ^ 1, (kt + 1) * 64);
        const int kb = kt * 64;
        const bf16_t* Kb = Ks[cur];
        const bf16_t* Vb = Vs[cur];
        const bool diag = (kt == nkt - 1);

        f32x4 sacc[4];
#pragma unroll
        for (int t = 0; t < 4; ++t) sacc[t] = (f32x4){0.f, 0.f, 0.f, 0.f};
#pragma unroll
        for (int t = 0; t < 4; ++t) {
            const bf16_t* krow = Kb + (t * 16 + c16) * 128;
#pragma unroll
            for (int cc = 0; cc < 4; ++cc) {
                bf16x8 kf = *(const bf16x8*)(krow + (((cc * 4 + g) ^ c7) * 8));
                sacc[t] = __builtin_amdgcn_mfma_f32_16x16x32_bf16(qf[cc], kf, sacc[t], 0, 0, 0);
            }
        }
        float p[4][4], alpha[4];
#pragma unroll
        for (int r = 0; r < 4; ++r) {
            int qq = qb + g * 4 + r;
            float s[4];
#pragma unroll
            for (int t = 0; t < 4; ++t)
                s[t] = (!diag || (kb + t * 16 + c16 <= qq)) ? sacc[t][r] : -1e30f;
            float mx = fmaxf(fmaxf(s[0], s[1]), fmaxf(s[2], s[3]));
            mx = fmaxf(mx, __shfl_xor(mx, 1));
            mx = fmaxf(mx, __shfl_xor(mx, 2));
            mx = fmaxf(mx, __shfl_xor(mx, 4));
            mx = fmaxf(mx, __shfl_xor(mx, 8));
            float mn = fmaxf(m[r], mx);
            alpha[r] = __expf(m[r] - mn);
            m[r] = mn;
            float rs = 0.f;
#pragma unroll
            for (int t = 0; t < 4; ++t) {
                p[t][r] = __expf(s[t] - mn);
                rs += p[t][r];
            }
            rs += __shfl_xor(rs, 1);
            rs += __shfl_xor(rs, 2);
            rs += __shfl_xor(rs, 4);
            rs += __shfl_xor(rs, 8);
            l[r] = l[r] * alpha[r] + rs;
        }
#pragma unroll
        for (int dt = 0; dt < 8; ++dt)
#pragma unroll
            for (int r = 0; r < 4; ++r) acc_o[dt][r] *= alpha[r];
#pragma unroll
        for (int t = 0; t < 4; ++t)
#pragma unroll
            for (int r = 0; r < 4; ++r)
                P[(g * 4 + r) * PLD + t * 16 + c16] = (bf16_t)p[t][r];
        bf16x8 pf[2];
        pf[0] = *(const bf16x8*)(P + c16 * PLD + g * 8);
        pf[1] = *(const bf16x8*)(P + c16 * PLD + 32 + g * 8);
#pragma unroll
        for (int dt = 0; dt < 8; ++dt) {
            const bf16_t* vrow = Vb + (dt * 16 + c16) * 64;
            bf16x8 vf0 = *(const bf16x8*)(vrow + ((g ^ c7) * 8));
            bf16x8 vf1 = *(const bf16x8*)(vrow + (((4 + g) ^ c7) * 8));
            acc_o[dt] = __builtin_amdgcn_mfma_f32_16x16x32_bf16(pf[0], vf0, acc_o[dt], 0, 0, 0);
            acc_o[dt] = __builtin_amdgcn_mfma_f32_16x16x32_bf16(pf[1], vf1, acc_o[dt], 0, 0, 0);
        }
        __syncthreads();
        cur ^= 1;
    }
    float inv_l[4];
#pragma unroll
    for (int r = 0; r < 4; ++r) inv_l[r] = 1.f / l[r];
#pragma unroll
    for (int dt = 0; dt < 8; ++dt)
#pragma unroll
        for (int r = 0; r < 4; ++r)
            O[(size_t)(qb + g * 4 + r) * HIDDEN + h * HD + dt * 16 + c16] =
                (bf16_t)(acc_o[dt][r] * inv_l[r]);
}

// ---------------- host ----------------
extern "C" void kernel_launch(void* const* d_in, const int* in_sizes, int n_in,
                              void* d_out, int out_size, void* d_ws, size_t ws_size,
                              hipStream_t stream) {
    const float* hs = (const float*)d_in[0];
    const float* Wq = (const float*)d_in[1];
    const float* Wk = (const float*)d_in[2];
    const float* Wv = (const float*)d_in[3];
    const float* Wo = (const float*)d_in[4];
    const int* pos = (const int*)d_in[6];
    float* out = (float*)d_out;

    char* ws = (char*)d_ws;
    size_t off = 0;
    auto alloc = [&](size_t bytes) -> void* {
        void* p = ws + off;
        off += (bytes + 255) & ~(size_t)255;
        return p;
    };
    bf16_t* hB    = (bf16_t*)alloc((size_t)S_LEN * HIDDEN * 2);
    bf16_t* WqkvT = (bf16_t*)alloc((size_t)NQKV * HIDDEN * 2);   // [6144][4096]
    bf16_t* WoT   = (bf16_t*)alloc((size_t)HIDDEN * HIDDEN * 2);
    float*  QKV   = (float*)alloc((size_t)S_LEN * NQKV * 4);     // [2048][6144]
    bf16_t* Qr    = (bf16_t*)alloc((size_t)NH * S_LEN * HD * 2);
    bf16_t* Kr    = (bf16_t*)alloc((size_t)NKV * S_LEN * HD * 2);
    bf16_t* Vt    = (bf16_t*)alloc((size_t)NKV * HD * S_LEN * 2);
    bf16_t* Oat   = (bf16_t*)alloc((size_t)S_LEN * HIDDEN * 2);

    dim3 tb(32, 8);
    // 1. cast hidden to bf16
    cast_bf16_kernel<<<2048, 256, 0, stream>>>(hs, hB, S_LEN * HIDDEN / 4);
    // 2. transpose-cast weights into fused [6144][4096]
    transpose_cast_kernel<<<dim3(HIDDEN / 32, HIDDEN / 32), tb, 0, stream>>>(Wq, WqkvT, HIDDEN, HIDDEN);
    transpose_cast_kernel<<<dim3(1024 / 32, HIDDEN / 32), tb, 0, stream>>>(Wk, WqkvT + (size_t)4096 * HIDDEN, 1024, HIDDEN);
    transpose_cast_kernel<<<dim3(1024 / 32, HIDDEN / 32), tb, 0, stream>>>(Wv, WqkvT + (size_t)5120 * HIDDEN, 1024, HIDDEN);
    transpose_cast_kernel<<<dim3(HIDDEN / 32, HIDDEN / 32), tb, 0, stream>>>(Wo, WoT, HIDDEN, HIDDEN);
    // 3. fused QKV projection: [2048][4096] @ [4096][6144]^T-layout -> [2048][6144]
    gemm8p_kernel<256, 256><<<(S_LEN / 256) * (NQKV / 256), 512, 0, stream>>>(hB, WqkvT, QKV, S_LEN, NQKV, HIDDEN);
    // 4. RoPE (fold 1/sqrt(128) into Q)
    rope_kernel<<<(S_LEN * NH * 64 + 255) / 256, 256, 0, stream>>>(QKV, Qr, pos, NH, NQKV, 0.08838834764831843f);
    rope_kernel<<<(S_LEN * NKV * 64 + 255) / 256, 256, 0, stream>>>(QKV + 4096, Kr, pos, NKV, NQKV, 1.0f);
    // 5. V transpose: [S][1024] (stride 6144) -> [1024][2048] == [NKV][128][S]
    transpose_cast_kernel<<<dim3(1024 / 32, S_LEN / 32), tb, 0, stream>>>(QKV + 5120, Vt, NQKV, S_LEN);
    // 6. flash attention
    attn_kernel<<<1024, 256, 0, stream>>>(Qr, Kr, Vt, Oat);
    // 7. output projection (BM=128 -> 256 blocks, full chip)
    gemm8p_kernel<128, 256><<<(S_LEN / 128) * (HIDDEN / 256), 512, 0, stream>>>(Oat, WoT, out, S_LEN, HIDDEN, HIDDEN);
}

// Round 5
// 409.134 us; speedup vs baseline: 2.2183x; 1.0632x over previous
//
#include <hip/hip_runtime.h>
#include <hip/hip_bf16.h>
#include <math.h>

#define S_LEN 2048
#define HIDDEN 4096
#define NH 32
#define NKV 8
#define HD 128
#define NQKV 6144   // NH*HD + 2*NKV*HD

typedef __bf16 bf16_t;
typedef __bf16 bf16x8 __attribute__((ext_vector_type(8)));
typedef __bf16 bf16x4 __attribute__((ext_vector_type(4)));
typedef float f32x4 __attribute__((ext_vector_type(4)));

typedef __attribute__((address_space(1))) void gvoid;
typedef __attribute__((address_space(3))) void lvoid;

__device__ __forceinline__ void gload_lds16(const void* g, void* l) {
    __builtin_amdgcn_global_load_lds((gvoid*)g, (lvoid*)l, 16, 0, 0);
}

// ---------------- cast fp32 -> bf16 (vectorized) ----------------
__global__ void cast_bf16_kernel(const float* __restrict__ in, bf16_t* __restrict__ out, int n4) {
    int stride = gridDim.x * blockDim.x;
    for (int idx = blockIdx.x * blockDim.x + threadIdx.x; idx < n4; idx += stride) {
        float4 v = ((const float4*)in)[idx];
        bf16x4 o;
        o.x = (bf16_t)v.x; o.y = (bf16_t)v.y; o.z = (bf16_t)v.z; o.w = (bf16_t)v.w;
        ((bf16x4*)out)[idx] = o;
    }
}

// ---------------- transpose + cast: in[R][C] (stride ldin) -> out[C][R] (stride ldout), bf16 ----------------
__global__ __launch_bounds__(256) void transpose_cast_kernel(const float* __restrict__ in,
                                                             bf16_t* __restrict__ out,
                                                             int ldin, int ldout) {
    __shared__ float t[32][33];
    int c0 = blockIdx.x * 32, r0 = blockIdx.y * 32;
    int tx = threadIdx.x, ty = threadIdx.y;
#pragma unroll
    for (int i = 0; i < 4; ++i)
        t[ty + i * 8][tx] = in[(size_t)(r0 + ty + i * 8) * ldin + c0 + tx];
    __syncthreads();
#pragma unroll
    for (int i = 0; i < 4; ++i)
        out[(size_t)(c0 + ty + i * 8) * ldout + r0 + tx] = (bf16_t)t[tx][ty + i * 8];
}

// ---------------- counted-vmcnt 4-phase GEMM: C[M][N] = A[M][K] @ Bt[N][K]^T ----------------
// BM x 256 tile, BK=64, 8 waves. Halves: A0/A1 = BM/2 rows, B0/B1 = 128 rows.
// Phase p of tile t: {ds_read frags | stage half p of tile t+1 | lgkmcnt(0) | MFMA quadrant}
// then gate {vmcnt(VN); s_barrier}. Phases compute quadrants (a-half,b-half):
// P0:(0,0) P1:(1,0) P2:(0,1) P3:(1,1). Stage order per tile: A0,B0,A1,B1.
// Ledger (per-thread loads/phase: BM=256:(2,2,2,2), BM=128:(1,2,1,2)):
//   gate before P0 of t needs A0(t),B0(t) (staged t-1 P0,P1); issued after = t-1 P2 + t-1 P3 = NLA+2
//   gate before P1 needs A1(t) (t-1 P2); issued after = t-1 P3 + t P0 = NLA+2
//   gate before P2 needs B1(t) (t-1 P3); issued after = t P0 + t P1 = NLA+2
// => uniform VN = NLA+2 (BM=256: 4, BM=128: 3), never 0 -> ~3 half-tiles in flight.
// Last tile wrap-stages tile 0 (never read) to keep counts uniform.
// Swizzle (rule #21): linear LDS dest, global chunk = (lane&7)^(lane>>3), ds_read chunk ^= row&7.
template<int BM>
__global__ __launch_bounds__(512, 2) void gemm4p_kernel(const bf16_t* __restrict__ A,
                                                        const bf16_t* __restrict__ Bt,
                                                        float* __restrict__ C,
                                                        int M, int N, int K) {
    constexpr int BN = 256, BK = 64;
    constexpr int MI = BM / 128;     // a-frags per quadrant (m dir)
    constexpr int PR = BM / 8;       // per-wave quadrant rows
    constexpr int NLA = BM / 128;    // A gloads per thread per half
    constexpr int VN = NLA + 2;      // counted vmcnt gate
    __shared__ bf16_t As[2][BM * BK];
    __shared__ bf16_t Bs[2][BN * BK];

    const int tid = threadIdx.x;
    const int lane = tid & 63, w = tid >> 6;
    const int qm = w >> 1, qn = w & 1;
    const int g = lane >> 4, c16 = lane & 15;
    const int srow = lane >> 3;
    const int scg = ((lane & 7) ^ srow) * 8;   // pre-swizzled global chunk (elem offset)

    // XCD swizzle, bm-fastest (each XCD reads few B panels, all A panels; K-slices L2-fit)
    const int nbm = M / BM;
    const int cpx = gridDim.x >> 3;
    const int bid = blockIdx.x;
    const int swz = (bid & 7) * cpx + (bid >> 3);
    const int bm = swz % nbm, bn = swz / nbm;

    const bf16_t* Ab = A + (size_t)(bm * BM) * K;
    const bf16_t* Bb = Bt + (size_t)(bn * BN) * K;

    auto stageA = [&](int buf, int kt, int half) {
#pragma unroll
        for (int j = 0; j < NLA; ++j) {
            int rbase = half * (BM / 2) + (w * NLA + j) * 8;
            gload_lds16(Ab + (size_t)(rbase + srow) * K + kt * BK + scg, &As[buf][rbase * BK]);
        }
    };
    auto stageB = [&](int buf, int kt, int half) {
#pragma unroll
        for (int j = 0; j < 2; ++j) {
            int rbase = half * 128 + (w * 2 + j) * 8;
            gload_lds16(Bb + (size_t)(rbase + srow) * K + kt * BK + scg, &Bs[buf][rbase * BK]);
        }
    };
    auto rdA = [&](int buf, int half, bf16x8 (&fr)[2][MI]) {
#pragma unroll
        for (int kk = 0; kk < 2; ++kk)
#pragma unroll
            for (int mi = 0; mi < MI; ++mi) {
                int row = half * (BM / 2) + qm * PR + mi * 16 + c16;
                fr[kk][mi] = *(const bf16x8*)&As[buf][row * BK + (((kk * 4 + g) ^ (row & 7)) * 8)];
            }
    };
    auto rdB = [&](int buf, int half, bf16x8 (&fr)[2][4]) {
#pragma unroll
        for (int kk = 0; kk < 2; ++kk)
#pragma unroll
            for (int ni = 0; ni < 4; ++ni) {
                int row = half * 128 + qn * 64 + ni * 16 + c16;
                fr[kk][ni] = *(const bf16x8*)&Bs[buf][row * BK + (((kk * 4 + g) ^ (row & 7)) * 8)];
            }
    };

#define GATE() do { asm volatile("s_waitcnt vmcnt(%0)" :: "n"(VN) : "memory"); \
                    __builtin_amdgcn_s_barrier(); \
                    __builtin_amdgcn_sched_barrier(0); } while (0)
#define LGKM() do { asm volatile("s_waitcnt lgkmcnt(0)" ::: "memory"); \
                    __builtin_amdgcn_sched_barrier(0); } while (0)

    f32x4 acc00[MI][4], acc10[MI][4], acc01[MI][4], acc11[MI][4];
#pragma unroll
    for (int mi = 0; mi < MI; ++mi)
#pragma unroll
        for (int ni = 0; ni < 4; ++ni) {
            acc00[mi][ni] = (f32x4){0.f, 0.f, 0.f, 0.f};
            acc10[mi][ni] = (f32x4){0.f, 0.f, 0.f, 0.f};
            acc01[mi][ni] = (f32x4){0.f, 0.f, 0.f, 0.f};
            acc11[mi][ni] = (f32x4){0.f, 0.f, 0.f, 0.f};
        }

    auto MM = [&](bf16x8 (&a)[2][MI], bf16x8 (&b)[2][4], f32x4 (&acc)[MI][4]) {
        __builtin_amdgcn_s_setprio(1);
#pragma unroll
        for (int kk = 0; kk < 2; ++kk)
#pragma unroll
            for (int mi = 0; mi < MI; ++mi)
#pragma unroll
                for (int ni = 0; ni < 4; ++ni)
                    acc[mi][ni] = __builtin_amdgcn_mfma_f32_16x16x32_bf16(a[kk][mi], b[kk][ni], acc[mi][ni], 0, 0, 0);
        __builtin_amdgcn_s_setprio(0);
    };

    const int NT = K / BK;
    // prologue: all 4 halves of tile 0
    stageA(0, 0, 0); stageB(0, 0, 0); stageA(0, 0, 1); stageB(0, 0, 1);

    for (int t = 0; t < NT; ++t) {
        const int buf = t & 1;
        const int nk = (t + 1 == NT) ? 0 : t + 1;   // wrap-stage keeps vmcnt ledger uniform
        bf16x8 a0[2][MI], a1[2][MI], b0[2][4], b1[2][4];
        GATE();                                     // A0,B0 of tile t landed
        // P0: quadrant (0,0)
        rdA(buf, 0, a0); rdB(buf, 0, b0);
        stageA(buf ^ 1, nk, 0);
        LGKM();
        MM(a0, b0, acc00);
        GATE();                                     // A1 landed
        // P1: quadrant (1,0)
        rdA(buf, 1, a1);
        stageB(buf ^ 1, nk, 0);
        LGKM();
        MM(a1, b0, acc10);
        GATE();                                     // B1 landed
        // P2: quadrant (0,1)
        rdB(buf, 1, b1);
        stageA(buf ^ 1, nk, 1);
        LGKM();
        MM(a0, b1, acc01);
        GATE();
        // P3: quadrant (1,1) (frags already in regs)
        stageB(buf ^ 1, nk, 1);
        MM(a1, b1, acc11);
        // tile-end gate is next iteration's leading GATE
    }
#undef GATE
#undef LGKM

    auto wr = [&](f32x4 (&acc)[MI][4], int ah, int bh) {
#pragma unroll
        for (int mi = 0; mi < MI; ++mi)
#pragma unroll
            for (int ni = 0; ni < 4; ++ni) {
                int col = bn * BN + bh * 128 + qn * 64 + ni * 16 + c16;
#pragma unroll
                for (int r = 0; r < 4; ++r) {
                    int row = bm * BM + ah * (BM / 2) + qm * PR + mi * 16 + g * 4 + r;
                    C[(size_t)row * N + col] = acc[mi][ni][r];
                }
            }
    };
    wr(acc00, 0, 0); wr(acc10, 1, 0); wr(acc01, 0, 1); wr(acc11, 1, 1);
}

// ---------------- RoPE: in fp32 [S][ld] (head block at col h*128) -> out bf16 [H][S][128] ----------------
__global__ void rope_kernel(const float* __restrict__ in, bf16_t* __restrict__ out,
                            const int* __restrict__ pos, int H, int ld, float scale) {
    int idx = blockIdx.x * blockDim.x + threadIdx.x;
    int total = S_LEN * H * 64;
    if (idx >= total) return;
    int d = idx & 63;
    int h = (idx >> 6) % H;
    int s = idx / (64 * H);
    const float* base = in + (size_t)s * ld + h * HD;
    float x0 = base[d], x1 = base[d + 64];
    float p = (float)pos[s];
    float invf = __expf(-0.14391156831212787f * (float)d);  // ln(10000)/64
    float f = p * invf;
    float sn, cs;
    __sincosf(f, &sn, &cs);
    float o0 = (x0 * cs - x1 * sn) * scale;
    float o1 = (x1 * cs + x0 * sn) * scale;
    bf16_t* ob = out + ((size_t)h * S_LEN + s) * HD;
    ob[d] = (bf16_t)o0;
    ob[d + 64] = (bf16_t)o1;
}

// ---------------- flash attention (cooperative LDS staging, 2-phase pipeline) ----------------
#define PLD 72
__global__ __launch_bounds__(256) void attn_kernel(const bf16_t* __restrict__ Q,
                                                   const bf16_t* __restrict__ K,
                                                   const bf16_t* __restrict__ Vt,
                                                   bf16_t* __restrict__ O) {
    __shared__ bf16_t Ks[2][64 * 128];   // [kv row][d], swizzled chunks
    __shared__ bf16_t Vs[2][128 * 64];   // [d][kv], swizzled chunks
    __shared__ bf16_t Pl[4][16 * PLD];
    const int tid = threadIdx.x;
    const int lane = tid & 63, w = tid >> 6;
    const int bid = blockIdx.x;
    const int h = bid & 31;
    const int x = bid >> 5;
    const int kv = h >> 2;               // N_REP = 4
    const int qb = x * 64 + w * 16;
    const int g = lane >> 4, c16 = lane & 15;
    const int c7 = c16 & 7;
    const bf16_t* Qh = Q + (size_t)h * S_LEN * HD;
    const bf16_t* Kh = K + (size_t)kv * S_LEN * HD;
    const bf16_t* Vh = Vt + (size_t)kv * HD * S_LEN;
    bf16_t* P = Pl[w];

    auto stage = [&](int buf, int kb) {
        bf16_t* Kd = Ks[buf];
        bf16_t* Vd = Vs[buf];
#pragma unroll
        for (int j = 0; j < 4; ++j) {
            int i = w * 4 + j;
            {   // K: instr covers 4 rows of 256B; lane l -> row 4i+(l>>4), chunk l&15
                int row = 4 * i + (lane >> 4);
                int sc = (lane & 15) ^ (row & 7);
                gload_lds16(Kh + (size_t)(kb + row) * HD + sc * 8, Kd + i * 512);
            }
            {   // V: instr covers 8 rows of 128B; lane l -> row 8i+(l>>3), chunk l&7
                int row = 8 * i + (lane >> 3);
                int sc = (lane & 7) ^ ((lane >> 3) & 7);
                gload_lds16(Vh + (size_t)row * S_LEN + kb + sc * 8, Vd + i * 512);
            }
        }
    };

    bf16x8 qf[4];
#pragma unroll
    for (int c = 0; c < 4; ++c)
        qf[c] = *(const bf16x8*)(Qh + (size_t)(qb + c16) * HD + c * 32 + g * 8);

    f32x4 acc_o[8];
#pragma unroll
    for (int dt = 0; dt < 8; ++dt) acc_o[dt] = (f32x4){0.f, 0.f, 0.f, 0.f};
    float m[4] = {-1e30f, -1e30f, -1e30f, -1e30f};
    float l[4] = {0.f, 0.f, 0.f, 0.f};

    const int nkt = x + 1;               // KVBLK=64; diagonal tile is last
    stage(0, 0);
    __syncthreads();
    int cur = 0;

    for (int kt = 0; kt < nkt; ++kt) {
        if (kt + 1 < nkt) stage(cur ^ 1, (kt + 1) * 64);
        const int kb = kt * 64;
        const bf16_t* Kb = Ks[cur];
        const bf16_t* Vb = Vs[cur];
        const bool diag = (kt == nkt - 1);

        f32x4 sacc[4];
#pragma unroll
        for (int t = 0; t < 4; ++t) sacc[t] = (f32x4){0.f, 0.f, 0.f, 0.f};
#pragma unroll
        for (int t = 0; t < 4; ++t) {
            const bf16_t* krow = Kb + (t * 16 + c16) * 128;
#pragma unroll
            for (int cc = 0; cc < 4; ++cc) {
                bf16x8 kf = *(const bf16x8*)(krow + (((cc * 4 + g) ^ c7) * 8));
                sacc[t] = __builtin_amdgcn_mfma_f32_16x16x32_bf16(qf[cc], kf, sacc[t], 0, 0, 0);
            }
        }
        float p[4][4], alpha[4];
#pragma unroll
        for (int r = 0; r < 4; ++r) {
            int qq = qb + g * 4 + r;
            float s[4];
#pragma unroll
            for (int t = 0; t < 4; ++t)
                s[t] = (!diag || (kb + t * 16 + c16 <= qq)) ? sacc[t][r] : -1e30f;
            float mx = fmaxf(fmaxf(s[0], s[1]), fmaxf(s[2], s[3]));
            mx = fmaxf(mx, __shfl_xor(mx, 1));
            mx = fmaxf(mx, __shfl_xor(mx, 2));
            mx = fmaxf(mx, __shfl_xor(mx, 4));
            mx = fmaxf(mx, __shfl_xor(mx, 8));
            float mn = fmaxf(m[r], mx);
            alpha[r] = __expf(m[r] - mn);
            m[r] = mn;
            float rs = 0.f;
#pragma unroll
            for (int t = 0; t < 4; ++t) {
                p[t][r] = __expf(s[t] - mn);
                rs += p[t][r];
            }
            rs += __shfl_xor(rs, 1);
            rs += __shfl_xor(rs, 2);
            rs += __shfl_xor(rs, 4);
            rs += __shfl_xor(rs, 8);
            l[r] = l[r] * alpha[r] + rs;
        }
#pragma unroll
        for (int dt = 0; dt < 8; ++dt)
#pragma unroll
            for (int r = 0; r < 4; ++r) acc_o[dt][r] *= alpha[r];
#pragma unroll
        for (int t = 0; t < 4; ++t)
#pragma unroll
            for (int r = 0; r < 4; ++r)
                P[(g * 4 + r) * PLD + t * 16 + c16] = (bf16_t)p[t][r];
        bf16x8 pf[2];
        pf[0] = *(const bf16x8*)(P + c16 * PLD + g * 8);
        pf[1] = *(const bf16x8*)(P + c16 * PLD + 32 + g * 8);
#pragma unroll
        for (int dt = 0; dt < 8; ++dt) {
            const bf16_t* vrow = Vb + (dt * 16 + c16) * 64;
            bf16x8 vf0 = *(const bf16x8*)(vrow + ((g ^ c7) * 8));
            bf16x8 vf1 = *(const bf16x8*)(vrow + (((4 + g) ^ c7) * 8));
            acc_o[dt] = __builtin_amdgcn_mfma_f32_16x16x32_bf16(pf[0], vf0, acc_o[dt], 0, 0, 0);
            acc_o[dt] = __builtin_amdgcn_mfma_f32_16x16x32_bf16(pf[1], vf1, acc_o[dt], 0, 0, 0);
        }
        __syncthreads();
        cur ^= 1;
    }
    float inv_l[4];
#pragma unroll
    for (int r = 0; r < 4; ++r) inv_l[r] = 1.f / l[r];
#pragma unroll
    for (int dt = 0; dt < 8; ++dt)
#pragma unroll
        for (int r = 0; r < 4; ++r)
            O[(size_t)(qb + g * 4 + r) * HIDDEN + h * HD + dt * 16 + c16] =
                (bf16_t)(acc_o[dt][r] * inv_l[r]);
}

// ---------------- host ----------------
extern "C" void kernel_launch(void* const* d_in, const int* in_sizes, int n_in,
                              void* d_out, int out_size, void* d_ws, size_t ws_size,
                              hipStream_t stream) {
    const float* hs = (const float*)d_in[0];
    const float* Wq = (const float*)d_in[1];
    const float* Wk = (const float*)d_in[2];
    const float* Wv = (const float*)d_in[3];
    const float* Wo = (const float*)d_in[4];
    const int* pos = (const int*)d_in[6];
    float* out = (float*)d_out;

    char* ws = (char*)d_ws;
    size_t off = 0;
    auto alloc = [&](size_t bytes) -> void* {
        void* p = ws + off;
        off += (bytes + 255) & ~(size_t)255;
        return p;
    };
    bf16_t* hB    = (bf16_t*)alloc((size_t)S_LEN * HIDDEN * 2);
    bf16_t* WqkvT = (bf16_t*)alloc((size_t)NQKV * HIDDEN * 2);   // [6144][4096]
    bf16_t* WoT   = (bf16_t*)alloc((size_t)HIDDEN * HIDDEN * 2);
    float*  QKV   = (float*)alloc((size_t)S_LEN * NQKV * 4);     // [2048][6144]
    bf16_t* Qr    = (bf16_t*)alloc((size_t)NH * S_LEN * HD * 2);
    bf16_t* Kr    = (bf16_t*)alloc((size_t)NKV * S_LEN * HD * 2);
    bf16_t* Vt    = (bf16_t*)alloc((size_t)NKV * HD * S_LEN * 2);
    bf16_t* Oat   = (bf16_t*)alloc((size_t)S_LEN * HIDDEN * 2);

    dim3 tb(32, 8);
    // 1. cast hidden to bf16
    cast_bf16_kernel<<<2048, 256, 0, stream>>>(hs, hB, S_LEN * HIDDEN / 4);
    // 2. transpose-cast weights into fused [6144][4096]
    transpose_cast_kernel<<<dim3(HIDDEN / 32, HIDDEN / 32), tb, 0, stream>>>(Wq, WqkvT, HIDDEN, HIDDEN);
    transpose_cast_kernel<<<dim3(1024 / 32, HIDDEN / 32), tb, 0, stream>>>(Wk, WqkvT + (size_t)4096 * HIDDEN, 1024, HIDDEN);
    transpose_cast_kernel<<<dim3(1024 / 32, HIDDEN / 32), tb, 0, stream>>>(Wv, WqkvT + (size_t)5120 * HIDDEN, 1024, HIDDEN);
    transpose_cast_kernel<<<dim3(HIDDEN / 32, HIDDEN / 32), tb, 0, stream>>>(Wo, WoT, HIDDEN, HIDDEN);
    // 3. fused QKV projection: [2048][4096] @ [4096][6144]^T-layout -> [2048][6144]
    gemm4p_kernel<256><<<(S_LEN / 256) * (NQKV / 256), 512, 0, stream>>>(hB, WqkvT, QKV, S_LEN, NQKV, HIDDEN);
    // 4. RoPE (fold 1/sqrt(128) into Q)
    rope_kernel<<<(S_LEN * NH * 64 + 255) / 256, 256, 0, stream>>>(QKV, Qr, pos, NH, NQKV, 0.08838834764831843f);
    rope_kernel<<<(S_LEN * NKV * 64 + 255) / 256, 256, 0, stream>>>(QKV + 4096, Kr, pos, NKV, NQKV, 1.0f);
    // 5. V transpose: [S][1024] (stride 6144) -> [1024][2048] == [NKV][128][S]
    transpose_cast_kernel<<<dim3(1024 / 32, S_LEN / 32), tb, 0, stream>>>(QKV + 5120, Vt, NQKV, S_LEN);
    // 6. flash attention
    attn_kernel<<<1024, 256, 0, stream>>>(Qr, Kr, Vt, Oat);
    // 7. output projection (BM=128 -> 256 blocks, full chip)
    gemm4p_kernel<128><<<(S_LEN / 128) * (HIDDEN / 256), 512, 0, stream>>>(Oat, WoT, out, S_LEN, HIDDEN, HIDDEN);
}

// Round 6
// 388.988 us; speedup vs baseline: 2.3332x; 1.0518x over previous
//
#include <hip/hip_runtime.h>
#include <hip/hip_bf16.h>
#include <math.h>

#define S_LEN 2048
#define HIDDEN 4096
#define NH 32
#define NKV 8
#define HD 128
#define NQKV 6144   // NH*HD + 2*NKV*HD

typedef __bf16 bf16_t;
typedef __bf16 bf16x8 __attribute__((ext_vector_type(8)));
typedef __bf16 bf16x4 __attribute__((ext_vector_type(4)));
typedef float f32x4 __attribute__((ext_vector_type(4)));

typedef __attribute__((address_space(1))) void gvoid;
typedef __attribute__((address_space(3))) void lvoid;

__device__ __forceinline__ void gload_lds16(const void* g, void* l) {
    __builtin_amdgcn_global_load_lds((gvoid*)g, (lvoid*)l, 16, 0, 0);
}

// ---------------- cast fp32 -> bf16 (vectorized) ----------------
__global__ void cast_bf16_kernel(const float* __restrict__ in, bf16_t* __restrict__ out, int n4) {
    int stride = gridDim.x * blockDim.x;
    for (int idx = blockIdx.x * blockDim.x + threadIdx.x; idx < n4; idx += stride) {
        float4 v = ((const float4*)in)[idx];
        bf16x4 o;
        o.x = (bf16_t)v.x; o.y = (bf16_t)v.y; o.z = (bf16_t)v.z; o.w = (bf16_t)v.w;
        ((bf16x4*)out)[idx] = o;
    }
}

// ---------------- transpose + cast: in[R][C] (stride ldin) -> out[C][R] (stride ldout), bf16 ----------------
__global__ __launch_bounds__(256) void transpose_cast_kernel(const float* __restrict__ in,
                                                             bf16_t* __restrict__ out,
                                                             int ldin, int ldout) {
    __shared__ float t[32][33];
    int c0 = blockIdx.x * 32, r0 = blockIdx.y * 32;
    int tx = threadIdx.x, ty = threadIdx.y;
#pragma unroll
    for (int i = 0; i < 4; ++i)
        t[ty + i * 8][tx] = in[(size_t)(r0 + ty + i * 8) * ldin + c0 + tx];
    __syncthreads();
#pragma unroll
    for (int i = 0; i < 4; ++i)
        out[(size_t)(c0 + ty + i * 8) * ldout + r0 + tx] = (bf16_t)t[tx][ty + i * 8];
}

// ---------------- ring-3 counted-vmcnt GEMM: C[M][N] = A[M][K] @ Bt[N][K]^T ----------------
// 128x256 tile, BK=32 per phase, 8 waves (2m x 4n, 64x64 out each), 512 threads.
// LDS ring of 3 K-chunk slots (A 8KB + B 16KB each) = 72 KiB -> 2 blocks/CU (16 waves/CU).
// Phase t: {vmcnt(3); barrier; 8 swizzled ds_read_b128; stage chunk t+2 -> slot (t+2)%3
//          (3 gload_lds); lgkmcnt(0); 16 MFMA}.
// Ledger: chunk t staged at phase t-2; outstanding at gate-t = stage(t-1) = 3 loads ->
// vmcnt(3) waits exactly for chunk t, never drains. Race-free: slot(t+2)%3 == slot(t-1),
// whose readers completed before barrier-t (lgkmcnt(0) precedes their MFMA; barrier orders).
// Wrap-stage on the last two phases keeps the vmcnt ledger uniform (writes never read).
// Swizzle (rule #21): LDS[r][c] = G[r][c ^ ((r>>1)&3)] via per-lane global source chunk
// (l&3)^((l>>3)&3); read back with chunk g ^ ((c16>>1)&3). Residual 2-way conflict = free.
__global__ __launch_bounds__(512, 2) void gemm_ring_kernel(const bf16_t* __restrict__ A,
                                                           const bf16_t* __restrict__ Bt,
                                                           float* __restrict__ C,
                                                           int M, int N, int K) {
    __shared__ bf16_t As[3][128 * 32];
    __shared__ bf16_t Bs[3][256 * 32];
    const int tid = threadIdx.x;
    const int lane = tid & 63, w = tid >> 6;
    const int wm = w >> 2, wn = w & 3;
    const int g = lane >> 4, c16 = lane & 15;
    const int srow = lane >> 2;                              // row within a 16-row DMA instr
    const int scg = ((lane & 3) ^ ((lane >> 3) & 3)) * 8;    // pre-swizzled global chunk (elems)
    const int rdc = (g ^ ((c16 >> 1) & 3)) * 8;              // swizzled read chunk (elems)

    // XCD swizzle, bm-fastest
    const int nbm = M / 128;
    const int cpx = gridDim.x >> 3;
    const int bid = blockIdx.x;
    const int swz = (bid & 7) * cpx + (bid >> 3);
    const int bm = swz % nbm, bn = swz / nbm;

    const bf16_t* Ab = A + (size_t)(bm * 128) * K;
    const bf16_t* Bb = Bt + (size_t)(bn * 256) * K;

    auto stage = [&](int slot, int kt) {
        const bf16_t* Ak = Ab + (size_t)kt * 32;
        const bf16_t* Bk = Bb + (size_t)kt * 32;
        {   // A: 8 instrs total, 1 per wave: rows 16w..16w+15
            int rb = 16 * w;
            gload_lds16(Ak + (size_t)(rb + srow) * K + scg, &As[slot][rb * 32]);
        }
#pragma unroll
        for (int j = 0; j < 2; ++j) {   // B: 16 instrs, 2 per wave
            int rb = 32 * w + 16 * j;
            gload_lds16(Bk + (size_t)(rb + srow) * K + scg, &Bs[slot][rb * 32]);
        }
    };

    f32x4 acc[4][4];
#pragma unroll
    for (int i = 0; i < 4; ++i)
#pragma unroll
        for (int j = 0; j < 4; ++j)
            acc[i][j] = (f32x4){0.f, 0.f, 0.f, 0.f};

    const int NT = K / 32;
    stage(0, 0);
    stage(1, 1);

    int slot = 0, slot2 = 2;           // slot = t%3, slot2 = (t+2)%3
    for (int t = 0; t < NT; ++t) {
        asm volatile("s_waitcnt vmcnt(3)" ::: "memory");
        __builtin_amdgcn_s_barrier();
        __builtin_amdgcn_sched_barrier(0);

        bf16x8 af[4], bf[4];
#pragma unroll
        for (int i = 0; i < 4; ++i) {
            int arow = wm * 64 + i * 16 + c16;
            af[i] = *(const bf16x8*)&As[slot][arow * 32 + rdc];
            int brow = wn * 64 + i * 16 + c16;
            bf[i] = *(const bf16x8*)&Bs[slot][brow * 32 + rdc];
        }
        int nk = t + 2;
        if (nk >= NT) nk -= NT;        // wrap-stage: keeps ledger uniform, never read
        stage(slot2, nk);

        asm volatile("s_waitcnt lgkmcnt(0)" ::: "memory");
        __builtin_amdgcn_sched_barrier(0);
        __builtin_amdgcn_s_setprio(1);
#pragma unroll
        for (int i = 0; i < 4; ++i)
#pragma unroll
            for (int j = 0; j < 4; ++j)
                acc[i][j] = __builtin_amdgcn_mfma_f32_16x16x32_bf16(af[i], bf[j], acc[i][j], 0, 0, 0);
        __builtin_amdgcn_s_setprio(0);

        slot = slot2;                  // (t+1)%3 == old (t+2)%3 - 1... advance both mod 3
        slot = (slot + 2) % 3;         // slot = old slot+1 mod 3
        slot2 = (slot + 2) % 3;
    }

#pragma unroll
    for (int mi = 0; mi < 4; ++mi)
#pragma unroll
        for (int ni = 0; ni < 4; ++ni) {
            int col = bn * 256 + wn * 64 + ni * 16 + c16;
#pragma unroll
            for (int r = 0; r < 4; ++r) {
                int row = bm * 128 + wm * 64 + mi * 16 + g * 4 + r;
                C[(size_t)row * N + col] = acc[mi][ni][r];
            }
        }
}

// ---------------- RoPE: in fp32 [S][ld] (head block at col h*128) -> out bf16 [H][S][128] ----------------
__global__ void rope_kernel(const float* __restrict__ in, bf16_t* __restrict__ out,
                            const int* __restrict__ pos, int H, int ld, float scale) {
    int idx = blockIdx.x * blockDim.x + threadIdx.x;
    int total = S_LEN * H * 64;
    if (idx >= total) return;
    int d = idx & 63;
    int h = (idx >> 6) % H;
    int s = idx / (64 * H);
    const float* base = in + (size_t)s * ld + h * HD;
    float x0 = base[d], x1 = base[d + 64];
    float p = (float)pos[s];
    float invf = __expf(-0.14391156831212787f * (float)d);  // ln(10000)/64
    float f = p * invf;
    float sn, cs;
    __sincosf(f, &sn, &cs);
    float o0 = (x0 * cs - x1 * sn) * scale;
    float o1 = (x1 * cs + x0 * sn) * scale;
    bf16_t* ob = out + ((size_t)h * S_LEN + s) * HD;
    ob[d] = (bf16_t)o0;
    ob[d + 64] = (bf16_t)o1;
}

// ---------------- flash attention (cooperative LDS staging, 2-phase pipeline) ----------------
#define PLD 72
__global__ __launch_bounds__(256) void attn_kernel(const bf16_t* __restrict__ Q,
                                                   const bf16_t* __restrict__ K,
                                                   const bf16_t* __restrict__ Vt,
                                                   bf16_t* __restrict__ O) {
    __shared__ bf16_t Ks[2][64 * 128];   // [kv row][d], swizzled chunks
    __shared__ bf16_t Vs[2][128 * 64];   // [d][kv], swizzled chunks
    __shared__ bf16_t Pl[4][16 * PLD];
    const int tid = threadIdx.x;
    const int lane = tid & 63, w = tid >> 6;
    const int bid = blockIdx.x;
    const int h = bid & 31;
    const int x = bid >> 5;
    const int kv = h >> 2;               // N_REP = 4
    const int qb = x * 64 + w * 16;
    const int g = lane >> 4, c16 = lane & 15;
    const int c7 = c16 & 7;
    const bf16_t* Qh = Q + (size_t)h * S_LEN * HD;
    const bf16_t* Kh = K + (size_t)kv * S_LEN * HD;
    const bf16_t* Vh = Vt + (size_t)kv * HD * S_LEN;
    bf16_t* P = Pl[w];

    auto stage = [&](int buf, int kb) {
        bf16_t* Kd = Ks[buf];
        bf16_t* Vd = Vs[buf];
#pragma unroll
        for (int j = 0; j < 4; ++j) {
            int i = w * 4 + j;
            {   // K: instr covers 4 rows of 256B; lane l -> row 4i+(l>>4), chunk l&15
                int row = 4 * i + (lane >> 4);
                int sc = (lane & 15) ^ (row & 7);
                gload_lds16(Kh + (size_t)(kb + row) * HD + sc * 8, Kd + i * 512);
            }
            {   // V: instr covers 8 rows of 128B; lane l -> row 8i+(l>>3), chunk l&7
                int row = 8 * i + (lane >> 3);
                int sc = (lane & 7) ^ ((lane >> 3) & 7);
                gload_lds16(Vh + (size_t)row * S_LEN + kb + sc * 8, Vd + i * 512);
            }
        }
    };

    bf16x8 qf[4];
#pragma unroll
    for (int c = 0; c < 4; ++c)
        qf[c] = *(const bf16x8*)(Qh + (size_t)(qb + c16) * HD + c * 32 + g * 8);

    f32x4 acc_o[8];
#pragma unroll
    for (int dt = 0; dt < 8; ++dt) acc_o[dt] = (f32x4){0.f, 0.f, 0.f, 0.f};
    float m[4] = {-1e30f, -1e30f, -1e30f, -1e30f};
    float l[4] = {0.f, 0.f, 0.f, 0.f};

    const int nkt = x + 1;               // KVBLK=64; diagonal tile is last
    stage(0, 0);
    __syncthreads();
    int cur = 0;

    for (int kt = 0; kt < nkt; ++kt) {
        if (kt + 1 < nkt) stage(cur ^ 1, (kt + 1) * 64);
        const int kb = kt * 64;
        const bf16_t* Kb = Ks[cur];
        const bf16_t* Vb = Vs[cur];
        const bool diag = (kt == nkt - 1);

        f32x4 sacc[4];
#pragma unroll
        for (int t = 0; t < 4; ++t) sacc[t] = (f32x4){0.f, 0.f, 0.f, 0.f};
#pragma unroll
        for (int t = 0; t < 4; ++t) {
            const bf16_t* krow = Kb + (t * 16 + c16) * 128;
#pragma unroll
            for (int cc = 0; cc < 4; ++cc) {
                bf16x8 kf = *(const bf16x8*)(krow + (((cc * 4 + g) ^ c7) * 8));
                sacc[t] = __builtin_amdgcn_mfma_f32_16x16x32_bf16(qf[cc], kf, sacc[t], 0, 0, 0);
            }
        }
        float p[4][4], alpha[4];
#pragma unroll
        for (int r = 0; r < 4; ++r) {
            int qq = qb + g * 4 + r;
            float s[4];
#pragma unroll
            for (int t = 0; t < 4; ++t)
                s[t] = (!diag || (kb + t * 16 + c16 <= qq)) ? sacc[t][r] : -1e30f;
            float mx = fmaxf(fmaxf(s[0], s[1]), fmaxf(s[2], s[3]));
            mx = fmaxf(mx, __shfl_xor(mx, 1));
            mx = fmaxf(mx, __shfl_xor(mx, 2));
            mx = fmaxf(mx, __shfl_xor(mx, 4));
            mx = fmaxf(mx, __shfl_xor(mx, 8));
            float mn = fmaxf(m[r], mx);
            alpha[r] = __expf(m[r] - mn);
            m[r] = mn;
            float rs = 0.f;
#pragma unroll
            for (int t = 0; t < 4; ++t) {
                p[t][r] = __expf(s[t] - mn);
                rs += p[t][r];
            }
            rs += __shfl_xor(rs, 1);
            rs += __shfl_xor(rs, 2);
            rs += __shfl_xor(rs, 4);
            rs += __shfl_xor(rs, 8);
            l[r] = l[r] * alpha[r] + rs;
        }
#pragma unroll
        for (int dt = 0; dt < 8; ++dt)
#pragma unroll
            for (int r = 0; r < 4; ++r) acc_o[dt][r] *= alpha[r];
#pragma unroll
        for (int t = 0; t < 4; ++t)
#pragma unroll
            for (int r = 0; r < 4; ++r)
                P[(g * 4 + r) * PLD + t * 16 + c16] = (bf16_t)p[t][r];
        bf16x8 pf[2];
        pf[0] = *(const bf16x8*)(P + c16 * PLD + g * 8);
        pf[1] = *(const bf16x8*)(P + c16 * PLD + 32 + g * 8);
#pragma unroll
        for (int dt = 0; dt < 8; ++dt) {
            const bf16_t* vrow = Vb + (dt * 16 + c16) * 64;
            bf16x8 vf0 = *(const bf16x8*)(vrow + ((g ^ c7) * 8));
            bf16x8 vf1 = *(const bf16x8*)(vrow + (((4 + g) ^ c7) * 8));
            acc_o[dt] = __builtin_amdgcn_mfma_f32_16x16x32_bf16(pf[0], vf0, acc_o[dt], 0, 0, 0);
            acc_o[dt] = __builtin_amdgcn_mfma_f32_16x16x32_bf16(pf[1], vf1, acc_o[dt], 0, 0, 0);
        }
        __syncthreads();
        cur ^= 1;
    }
    float inv_l[4];
#pragma unroll
    for (int r = 0; r < 4; ++r) inv_l[r] = 1.f / l[r];
#pragma unroll
    for (int dt = 0; dt < 8; ++dt)
#pragma unroll
        for (int r = 0; r < 4; ++r)
            O[(size_t)(qb + g * 4 + r) * HIDDEN + h * HD + dt * 16 + c16] =
                (bf16_t)(acc_o[dt][r] * inv_l[r]);
}

// ---------------- host ----------------
extern "C" void kernel_launch(void* const* d_in, const int* in_sizes, int n_in,
                              void* d_out, int out_size, void* d_ws, size_t ws_size,
                              hipStream_t stream) {
    const float* hs = (const float*)d_in[0];
    const float* Wq = (const float*)d_in[1];
    const float* Wk = (const float*)d_in[2];
    const float* Wv = (const float*)d_in[3];
    const float* Wo = (const float*)d_in[4];
    const int* pos = (const int*)d_in[6];
    float* out = (float*)d_out;

    char* ws = (char*)d_ws;
    size_t off = 0;
    auto alloc = [&](size_t bytes) -> void* {
        void* p = ws + off;
        off += (bytes + 255) & ~(size_t)255;
        return p;
    };
    bf16_t* hB    = (bf16_t*)alloc((size_t)S_LEN * HIDDEN * 2);
    bf16_t* WqkvT = (bf16_t*)alloc((size_t)NQKV * HIDDEN * 2);   // [6144][4096]
    bf16_t* WoT   = (bf16_t*)alloc((size_t)HIDDEN * HIDDEN * 2);
    float*  QKV   = (float*)alloc((size_t)S_LEN * NQKV * 4);     // [2048][6144]
    bf16_t* Qr    = (bf16_t*)alloc((size_t)NH * S_LEN * HD * 2);
    bf16_t* Kr    = (bf16_t*)alloc((size_t)NKV * S_LEN * HD * 2);
    bf16_t* Vt    = (bf16_t*)alloc((size_t)NKV * HD * S_LEN * 2);
    bf16_t* Oat   = (bf16_t*)alloc((size_t)S_LEN * HIDDEN * 2);

    dim3 tb(32, 8);
    // 1. cast hidden to bf16
    cast_bf16_kernel<<<2048, 256, 0, stream>>>(hs, hB, S_LEN * HIDDEN / 4);
    // 2. transpose-cast weights into fused [6144][4096]
    transpose_cast_kernel<<<dim3(HIDDEN / 32, HIDDEN / 32), tb, 0, stream>>>(Wq, WqkvT, HIDDEN, HIDDEN);
    transpose_cast_kernel<<<dim3(1024 / 32, HIDDEN / 32), tb, 0, stream>>>(Wk, WqkvT + (size_t)4096 * HIDDEN, 1024, HIDDEN);
    transpose_cast_kernel<<<dim3(1024 / 32, HIDDEN / 32), tb, 0, stream>>>(Wv, WqkvT + (size_t)5120 * HIDDEN, 1024, HIDDEN);
    transpose_cast_kernel<<<dim3(HIDDEN / 32, HIDDEN / 32), tb, 0, stream>>>(Wo, WoT, HIDDEN, HIDDEN);
    // 3. fused QKV projection: [2048][4096] @ [4096][6144]^T-layout -> [2048][6144]
    gemm_ring_kernel<<<(S_LEN / 128) * (NQKV / 256), 512, 0, stream>>>(hB, WqkvT, QKV, S_LEN, NQKV, HIDDEN);
    // 4. RoPE (fold 1/sqrt(128) into Q)
    rope_kernel<<<(S_LEN * NH * 64 + 255) / 256, 256, 0, stream>>>(QKV, Qr, pos, NH, NQKV, 0.08838834764831843f);
    rope_kernel<<<(S_LEN * NKV * 64 + 255) / 256, 256, 0, stream>>>(QKV + 4096, Kr, pos, NKV, NQKV, 1.0f);
    // 5. V transpose: [S][1024] (stride 6144) -> [1024][2048] == [NKV][128][S]
    transpose_cast_kernel<<<dim3(1024 / 32, S_LEN / 32), tb, 0, stream>>>(QKV + 5120, Vt, NQKV, S_LEN);
    // 6. flash attention
    attn_kernel<<<1024, 256, 0, stream>>>(Qr, Kr, Vt, Oat);
    // 7. output projection
    gemm_ring_kernel<<<(S_LEN / 128) * (HIDDEN / 256), 512, 0, stream>>>(Oat, WoT, out, S_LEN, HIDDEN, HIDDEN);
}